// Round 4
// baseline (337.081 us; speedup 1.0000x reference)
//
#include <hip/hip_runtime.h>
#include <stdint.h>

// Problem constants (fixed by the reference setup_inputs)
#define BATCH 128
#define SEQN  384                         // a rows (DP rows i)
#define SEQM  384                         // b rows (DP columns j)
#define DIM   128
#define KINF   1000000.0f                 // reference pseudo-infinity (nat units)
#define LOG2E  1.4426950408889634f
#define LN2    0.6931471805599453f
#define KINF2  (KINF * LOG2E)             // pseudo-infinity in base-2-scaled units

// Geometry: 2 blocks per batch (row halves), full half-matrix in LDS
#define HCOLS  388                        // 384 D-cols + 4 KINF2 pad cols
#define CSTR   200                        // ushorts per LDS column (192 data + 8 pad)
#define OFF1   162                        // h=1 column lag: 128 + 2*SLACK (verified r3)
#define SLACK  17                         // boundary read lag in PHASE2 units (verified r3)
#define BND_SLOTS 512                     // non-wrapping boundary slots per batch

// hardware base-2 transcendentals (v_exp_f32 / v_log_f32)
#define EXP2F(x) __builtin_amdgcn_exp2f(x)
#define LOG2F(x) __builtin_amdgcn_logf(x)

#define WG __HIP_MEMORY_SCOPE_WORKGROUP
#define AG __HIP_MEMORY_SCOPE_AGENT

typedef __attribute__((ext_vector_type(8))) short bf16x8;   // 8 bf16 = 4 VGPRs (MFMA A/B frag)
typedef __attribute__((ext_vector_type(4))) float f32x4;    // MFMA C/D frag

__device__ __forceinline__ unsigned short bf16_rne(float x) {
    uint32_t u = __float_as_uint(x);
    u += 0x7FFFu + ((u >> 16) & 1u);
    return (unsigned short)(u >> 16);
}
__device__ __forceinline__ uint32_t bf16_pair(float x, float y) {
    uint32_t ux = __float_as_uint(x); ux += 0x7FFFu + ((ux >> 16) & 1u);
    uint32_t uy = __float_as_uint(y); uy += 0x7FFFu + ((uy >> 16) & 1u);
    return (ux >> 16) | (uy & 0xFFFF0000u);
}

union frag_u { bf16x8 v; uint32_t u[4]; };
struct us3 { unsigned short u[3]; };
union BU { float2 f; unsigned long long u; };

// ---------------------------------------------------------------------------
// 256 blocks = 128 batches x 2 row-halves. Per block (256 thr, ~156 KB LDS,
// 1 block/CU):
//   wave 0   : soft-DTW DP for its 192 rows (3 rows/lane), round-3-verified
//              per-cell code. Refills from LDS (full half-matrix, no ring).
//   waves 1-3: producers, round-2-verified chunk pipeline. Chunk k = D cols
//              [32k,32k+32): B-frags from global, 4 si-groups/wave (A from
//              global, 1-deep prefetch), MFMA, bf16 -> ldsD. Free-running.
// Cross-block (one-way, h=0 -> h=1): bottom-row {botA,botB} per PHASE2 into
// a non-wrapping global slot array (agent relaxed u64 stores), progress
// published every 8 PHASE2s (agent release). h=1 reads slots with SLACK=17
// lag through a 4-deep register FIFO of agent relaxed loads, gated every 4
// pairs on the published progress (cached). No cycles in the wait graph.
// ---------------------------------------------------------------------------
__global__ __launch_bounds__(256) void fused_dtw(
        const float* __restrict__ A, const float* __restrict__ B,
        unsigned long long* __restrict__ bnd, int* __restrict__ w0prog,
        float* __restrict__ out) {
    __shared__ __align__(16) unsigned short ldsD[HCOLS * CSTR];  // 155,200 B
    __shared__ __align__(16) float normA[192];                   //     768 B
    __shared__ int prod_done[16];

    const int bx   = blockIdx.x;
    const int bat  = bx >> 1;
    const int h    = bx & 1;               // row half: rows 192h .. 192h+191
    const int tid  = threadIdx.x;
    const int wv   = tid >> 6;
    const int lane = tid & 63;

    if (tid < 16) prod_done[tid] = 0;
    __syncthreads();                       // only block-wide sync in the kernel

    unsigned long long* __restrict__ bndB = bnd + (long)bat * BND_SLOTS;
    int* __restrict__ w0p = w0prog + bat;

    if (wv != 0) {
        // ========================= PRODUCERS (waves 1..3) ====================
        const int l16 = lane & 15, q = lane >> 4;
        const int sbase = (wv - 1) * 4;    // this wave's si-groups (of 12)
        const float* __restrict__ Ab = A + ((long)bat * SEQN + 192 * h) * DIM;
        const float* __restrict__ Bb = B + (long)bat * SEQM * DIM;
        bool first = true;
        for (int k = 0; k < 13; k++) {
            if (k == 12) {
                // pad cols 384..387 = KINF2 (INF-flow right edge)
                if (wv == 1) {
                    uint32_t pv = bf16_pair(KINF2, KINF2);
                    int c = lane >> 4, i16 = lane & 15;      // 4 cols x 16 lanes
                    uint32_t* p = (uint32_t*)&ldsD[(384 + c) * CSTR] + i16 * 6;
                    #pragma unroll
                    for (int j = 0; j < 6; j++) p[j] = pv;   // 16*6 = 96 dw = 192 us
                }
            } else {
                // B fragments for 32 cols (2 j-groups of 16) + b-norms
                frag_u bfrag[2][4];
                float bn[2];
                #pragma unroll
                for (int jg = 0; jg < 2; jg++) {
                    const float* bp = Bb + (long)(32 * k + jg * 16 + l16) * DIM + q * 8;
                    float s = 0.0f;
                    #pragma unroll
                    for (int kk = 0; kk < 4; kk++) {
                        float4 w0 = *(const float4*)(bp + kk * 32);
                        float4 w1 = *(const float4*)(bp + kk * 32 + 4);
                        bfrag[jg][kk].u[0] = bf16_pair(w0.x, w0.y);
                        bfrag[jg][kk].u[1] = bf16_pair(w0.z, w0.w);
                        bfrag[jg][kk].u[2] = bf16_pair(w1.x, w1.y);
                        bfrag[jg][kk].u[3] = bf16_pair(w1.z, w1.w);
                        s += w0.x*w0.x + w0.y*w0.y + w0.z*w0.z + w0.w*w0.w
                           + w1.x*w1.x + w1.y*w1.y + w1.z*w1.z + w1.w*w1.w;
                    }
                    s += __shfl_xor(s, 16, 64);
                    s += __shfl_xor(s, 32, 64);
                    bn[jg] = s;
                }
                // this wave's 4 si-groups, 1-deep prefetched
                float4 c0v[4], c1v[4];
                {
                    const float* ap = Ab + (long)(sbase * 16 + l16) * DIM + q * 8;
                    #pragma unroll
                    for (int kk = 0; kk < 4; kk++) {
                        c0v[kk] = *(const float4*)(ap + kk * 32);
                        c1v[kk] = *(const float4*)(ap + kk * 32 + 4);
                    }
                }
                #pragma unroll
                for (int s4 = 0; s4 < 4; s4++) {
                    const int si = sbase + s4;
                    float4 n0[4], n1[4];
                    if (s4 < 3) {
                        const float* ap = Ab + (long)((si + 1) * 16 + l16) * DIM + q * 8;
                        #pragma unroll
                        for (int kk = 0; kk < 4; kk++) {
                            n0[kk] = *(const float4*)(ap + kk * 32);
                            n1[kk] = *(const float4*)(ap + kk * 32 + 4);
                        }
                    }
                    frag_u afr[4];
                    #pragma unroll
                    for (int kk = 0; kk < 4; kk++) {
                        afr[kk].u[0] = bf16_pair(c0v[kk].x, c0v[kk].y);
                        afr[kk].u[1] = bf16_pair(c0v[kk].z, c0v[kk].w);
                        afr[kk].u[2] = bf16_pair(c1v[kk].x, c1v[kk].y);
                        afr[kk].u[3] = bf16_pair(c1v[kk].z, c1v[kk].w);
                    }
                    if (first) {           // this wave's normA slice (own rows)
                        float sa = 0.0f;
                        #pragma unroll
                        for (int kk = 0; kk < 4; kk++)
                            sa += c0v[kk].x*c0v[kk].x + c0v[kk].y*c0v[kk].y
                                + c0v[kk].z*c0v[kk].z + c0v[kk].w*c0v[kk].w
                                + c1v[kk].x*c1v[kk].x + c1v[kk].y*c1v[kk].y
                                + c1v[kk].z*c1v[kk].z + c1v[kk].w*c1v[kk].w;
                        sa += __shfl_xor(sa, 16, 64);
                        sa += __shfl_xor(sa, 32, 64);
                        if (q == 0) normA[si * 16 + l16] = sa;
                    }
                    f32x4 acc0 = {0.0f, 0.0f, 0.0f, 0.0f};
                    f32x4 acc1 = {0.0f, 0.0f, 0.0f, 0.0f};
                    #pragma unroll
                    for (int kk = 0; kk < 4; kk++) {
                        acc0 = __builtin_amdgcn_mfma_f32_16x16x32_bf16(
                                   afr[kk].v, bfrag[0][kk].v, acc0, 0, 0, 0);
                        acc1 = __builtin_amdgcn_mfma_f32_16x16x32_bf16(
                                   afr[kk].v, bfrag[1][kk].v, acc1, 0, 0, 0);
                    }
                    if (first) asm volatile("s_waitcnt lgkmcnt(0)" ::: "memory");
                    float4 an = *(const float4*)&normA[si * 16 + q * 4];
                    #pragma unroll
                    for (int jg = 0; jg < 2; jg++) {
                        int col = 32 * k + jg * 16 + l16;
                        f32x4 ac = jg ? acc1 : acc0;
                        ushort4 pk;
                        pk.x = bf16_rne((an.x + bn[jg] - 2.0f * ac[0]) * LOG2E);
                        pk.y = bf16_rne((an.y + bn[jg] - 2.0f * ac[1]) * LOG2E);
                        pk.z = bf16_rne((an.z + bn[jg] - 2.0f * ac[2]) * LOG2E);
                        pk.w = bf16_rne((an.w + bn[jg] - 2.0f * ac[3]) * LOG2E);
                        *(ushort4*)&ldsD[col * CSTR + si * 16 + q * 4] = pk;
                    }
                    if (s4 < 3) {
                        #pragma unroll
                        for (int kk = 0; kk < 4; kk++) { c0v[kk] = n0[kk]; c1v[kk] = n1[kk]; }
                    }
                }
                first = false;
            }
            if (lane == 0)   // lane-0 only: counter==3 truly means all 3 waves
                __hip_atomic_fetch_add(&prod_done[k], 1, __ATOMIC_RELEASE, WG);
        }
        return;
    }

    // ====================== CONSUMER (wave 0): soft-DTW DP ===================
    const int  t     = lane;
    const bool isl0  = (t == 0);
    const int  off   = h ? OFF1 : 0;
    const int  npair = h ? 168 : 160;
    const unsigned short* __restrict__ ldsT = ldsD + 3 * t;

    {   int g = 0;
        while (__hip_atomic_load(&prod_done[0], __ATOMIC_ACQUIRE, WG) < 3)
            if (++g > (1 << 20)) break; }

    float prev[3];
    #pragma unroll
    for (int r = 0; r < 3; r++) prev[r] = KINF2;

    us3 dslot[4];                          // slot qq holds D column (c0 + qq)
    #pragma unroll
    for (int qq = 0; qq < 4; qq++) {
        int c = qq - 2 * t - off;
        int cc = c < 0 ? 0 : c;
        const unsigned short* p = ldsT + cc * CSTR;
        dslot[qq].u[0] = p[0]; dslot[qq].u[1] = p[1]; dslot[qq].u[2] = p[2];
    }

    float rcv0 = KINF2, rcv1 = KINF2, old_diag = KINF2;
    float lane0_diag = h ? KINF2 : 0.0f;   // R[0][0] seed lives in h=0 only
    float b_rcv0 = KINF2, b_rcv1 = KINF2, b_old = KINF2;   // h=1 boundary regs
    float botA = KINF2, botB = KINF2;
    float2 bq0, bq1, bq2, bq3;             // 4-deep boundary prefetch FIFO
    bq0 = bq1 = bq2 = bq3 = make_float2(KINF2, KINF2);
    int c0 = -2 * t - off;
    int kdone = 0, w0seen = -1;

#define UNPACK3(d, w)                                                       \
    d[0] = __uint_as_float(((uint32_t)w.u[0]) << 16);                       \
    d[1] = __uint_as_float(((uint32_t)w.u[1]) << 16);                       \
    d[2] = __uint_as_float(((uint32_t)w.u[2]) << 16);

#define COLPASS(dX, diag0, upseed, LEFTV, NEWV)                             \
    {                                                                       \
        float Bp = (upseed), Fp = 1.0f;                                     \
        float Bv[3], Fv[3];                                                 \
        _Pragma("unroll")                                                   \
        for (int r = 0; r < 3; r++) {                                       \
            float vd = (r == 0) ? (diag0) : LEFTV[r - 1];                   \
            float vl = LEFTV[r];                                            \
            float m3 = fminf(fminf(vd, vl), Bp);     /* v_min3_f32 */       \
            float al = EXP2F(m3 - Bp);                                      \
            float be = EXP2F(m3 - vd) + EXP2F(m3 - vl);                     \
            float Fr = __builtin_fmaf(al, Fp, be);                          \
            float Br = dX[r] + m3;                                          \
            Bv[r] = Br; Fv[r] = Fr;                                         \
            Bp = Br; Fp = Fr;                                               \
        }                                                                   \
        _Pragma("unroll")                                                   \
        for (int r = 0; r < 3; r++)                                         \
            NEWV[r] = Bv[r] - LOG2F(Fv[r]);                                 \
    }

#define PHASE2(Q)                                                           \
    {                                                                       \
        us3 wA = dslot[Q];                                                  \
        us3 wB = dslot[(Q) + 1];                                            \
        {   /* refill both slots for phase p+2 from LDS */                  \
            int cnA = c0 + 4;                                               \
            int ccA = cnA < 0 ? 0 : (cnA > 387 ? 387 : cnA);                \
            int cnB = c0 + 5;                                               \
            int ccB = cnB < 0 ? 0 : (cnB > 387 ? 387 : cnB);                \
            const unsigned short* pA = ldsT + ccA * CSTR;                   \
            const unsigned short* pB = ldsT + ccB * CSTR;                   \
            dslot[Q].u[0]       = pA[0];                                    \
            dslot[Q].u[1]       = pA[1];                                    \
            dslot[Q].u[2]       = pA[2];                                    \
            dslot[(Q) + 1].u[0] = pB[0];                                    \
            dslot[(Q) + 1].u[1] = pB[1];                                    \
            dslot[(Q) + 1].u[2] = pB[2];                                    \
        }                                                                   \
        float dA[3], dB[3];                                                 \
        UNPACK3(dA, wA)                                                     \
        UNPACK3(dB, wB)                                                     \
        float dgA = isl0 ? (h ? b_old  : lane0_diag) : old_diag;            \
        float upA = isl0 ? (h ? b_rcv0 : KINF2)      : rcv0;                \
        float upB = isl0 ? (h ? b_rcv1 : KINF2)      : rcv1;                \
        float newA[3];                                                      \
        COLPASS(dA, dgA, upA, prev, newA)                                   \
        COLPASS(dB, upA, upB, newA, prev)                                   \
        old_diag = rcv1;                                                    \
        rcv0 = __shfl_up(newA[2], 1, 64);                                   \
        rcv1 = __shfl_up(prev[2], 1, 64);                                   \
        botA = newA[2]; botB = prev[2];                                     \
        lane0_diag = KINF2;                                                 \
        c0 += 2;                                                            \
    }

    // TAIL0 (h=0): stream bottom row to global, publish progress every 8.
#define TAIL0(m)                                                            \
    {                                                                       \
        if (t == 63) {                                                      \
            BU bu; bu.f = make_float2(botA, botB);                          \
            __hip_atomic_store(&bndB[m], bu.u, __ATOMIC_RELAXED, AG);       \
            if (((m) & 7) == 7)                                             \
                __hip_atomic_store(w0p, (m), __ATOMIC_RELEASE, AG);         \
        }                                                                   \
    }
    // TAIL1 (h=1): consume slot n-SLACK via the 4-deep prefetch FIFO.
#define TAIL1(n)                                                            \
    {                                                                       \
        b_old = b_rcv1;                                                     \
        if ((n) >= SLACK) { b_rcv0 = bq0.x; b_rcv1 = bq0.y; }               \
        else              { b_rcv0 = KINF2; b_rcv1 = KINF2; }               \
        bq0 = bq1; bq1 = bq2; bq2 = bq3;                                    \
        int sl = (n) + 4 - SLACK;                                           \
        if (sl >= 0) {                                                      \
            BU bu;                                                          \
            bu.u = __hip_atomic_load(&bndB[sl], __ATOMIC_RELAXED, AG);      \
            bq3 = bu.f;                                                     \
        }                                                                   \
    }

    for (int p = 0; p < npair; p++) {
        if ((p & 3) == 3) {
            // chunk gate: refills of pairs p..p+3 touch cols <= 4p+19-off
            int kr = (4 * p + 19 - off) >> 5;
            if (kr > 12) kr = 12;
            if (kr > kdone) {
                int g = 0;
                while (__hip_atomic_load(&prod_done[kr], __ATOMIC_ACQUIRE, WG) < 3)
                    if (++g > (1 << 20)) break;
                kdone = kr;
            }
            if (h) {
                // boundary availability: FIFO loads during pairs p..p+3 target
                // slots <= 2p+7+4-SLACK = 2p-6 (SLACK=17). Cached check.
                int thr = 2 * p - 6;
                if (thr > 319) thr = 319;  // h=0's last publish is m=319
                if (thr >= 0 && w0seen < thr) {
                    int g = 0, v = w0seen;
                    do {
                        v = __hip_atomic_load(w0p, __ATOMIC_ACQUIRE, AG);
                    } while (v < thr && ++g < (1 << 20));
                    w0seen = v;
                }
            }
        }
        PHASE2(0)
        if (h == 0) { TAIL0(2 * p) } else { TAIL1(2 * p) }
        PHASE2(2)
        if (h == 0) { TAIL0(2 * p + 1) } else { TAIL1(2 * p + 1) }
    }
#undef PHASE2
#undef COLPASS
#undef UNPACK3
#undef TAIL0
#undef TAIL1

    // h=1 lane63, last PHASE2 colB = D-col 383 (DP j=384): prev[2] = R[384][384]
    if (h == 1 && t == 63) out[bat] = prev[2] * LN2;
}

// ---------------------------------------------------------------------------
extern "C" void kernel_launch(void* const* d_in, const int* in_sizes, int n_in,
                              void* d_out, int out_size, void* d_ws, size_t ws_size,
                              hipStream_t stream) {
    (void)in_sizes; (void)n_in; (void)out_size; (void)ws_size;
    const float* a = (const float*)d_in[0];
    const float* b = (const float*)d_in[1];
    float* out = (float*)d_out;

    // ws layout: [0, 512KB) boundary slots (128 x 512 x u64);
    //            [512KB, +512B) w0prog[128] (init -1 via memset 0xFF)
    unsigned long long* bnd = (unsigned long long*)d_ws;
    int* w0prog = (int*)((char*)d_ws + (size_t)BATCH * BND_SLOTS * 8);

    hipMemsetAsync(w0prog, 0xFF, BATCH * sizeof(int), stream);
    fused_dtw<<<dim3(2 * BATCH), dim3(256), 0, stream>>>(a, b, bnd, w0prog, out);
}

// Round 5
// 223.623 us; speedup vs baseline: 1.5074x; 1.5074x over previous
//
#include <hip/hip_runtime.h>
#include <stdint.h>

// Problem constants (fixed by the reference setup_inputs)
#define BATCH 128
#define SEQN  384                         // a rows (DP rows i)
#define SEQM  384                         // b rows (DP columns j)
#define DIM   128
#define KINF   1000000.0f                 // reference pseudo-infinity (nat units)
#define LOG2E  1.4426950408889634f
#define LN2    0.6931471805599453f
#define KINF2  (KINF * LOG2E)             // pseudo-infinity in base-2-scaled units

// Geometry: one block per batch; 2 consumer waves (3 rows/lane) + 2 producers.
#define RSLOTS 200                        // ring slots per half: 196 data + 4 pad
#define CSTR   196                        // ushorts per ring column (192 data + 4 pad)
#define OFF1   194                        // wave1 column lag = 128 + 2*SLACK
#define SLACK  33                         // boundary read lag in PHASE2 units
#define NPAIR0 160                        // wave0: 320 PHASE2s (bring slots 0..319)
#define NPAIR1 176                        // wave1: 352 PHASE2s (finishes col 383)
#define NPROD  2                          // producer waves per block

// hardware base-2 transcendentals (v_exp_f32 / v_log_f32)
#define EXP2F(x) __builtin_amdgcn_exp2f(x)
#define LOG2F(x) __builtin_amdgcn_logf(x)

#define WG __HIP_MEMORY_SCOPE_WORKGROUP

typedef __attribute__((ext_vector_type(8))) short bf16x8;   // 8 bf16 = 4 VGPRs (MFMA A/B frag)
typedef __attribute__((ext_vector_type(4))) float f32x4;    // MFMA C/D frag

__device__ __forceinline__ unsigned short bf16_rne(float x) {
    uint32_t u = __float_as_uint(x);
    u += 0x7FFFu + ((u >> 16) & 1u);
    return (unsigned short)(u >> 16);
}
__device__ __forceinline__ uint32_t bf16_pair(float x, float y) {
    uint32_t ux = __float_as_uint(x); ux += 0x7FFFu + ((ux >> 16) & 1u);
    uint32_t uy = __float_as_uint(y); uy += 0x7FFFu + ((uy >> 16) & 1u);
    return (ux >> 16) | (uy & 0xFFFF0000u);
}

union frag_u { bf16x8 v; uint32_t u[4]; };
struct us3 { unsigned short u[3]; };

#define SPIN_GE(addr, val)                                                   \
    { int g_ = 0;                                                            \
      while (__hip_atomic_load((addr), __ATOMIC_ACQUIRE, WG) < (val))        \
          if (++g_ > (1 << 21)) break; }

// ---------------------------------------------------------------------------
// One block per batch (128 blocks, 256 thr, ~157 KB LDS, 1 block/CU):
//   wave 0: DP rows 0..191   (3 rows/lane), reads ring0, streams bottom row
//           into bring[] (non-wrapping, 320 slots) + cons_prog[0] every 8.
//   wave 1: DP rows 192..383, off=194, reads ring1 + bring (2-deep reg FIFO,
//           lag SLACK=33), publishes cons_prog[1], writes out.
//   waves 2,3: producers. Task (k,hh) = D cols [32k,32k+32) x rows
//           [192hh,192hh+192): B-frags from global, 6 si-groups/wave with
//           1-deep A prefetch, MFMA, bf16 -> ring[hh]. Ring-wrap gates on the
//           owning consumer's progress only (window ~20 PHASE2s vs task ~7).
// Wait graph: producers -> consumers -> (nothing): deadlock-free by shape.
// ---------------------------------------------------------------------------
__global__ __launch_bounds__(256) void fused_dtw(
        const float* __restrict__ A, const float* __restrict__ B,
        float* __restrict__ out) {
    __shared__ __align__(16) unsigned short ring0[RSLOTS * CSTR]; // 78,400 B
    __shared__ __align__(16) unsigned short ring1[RSLOTS * CSTR]; // 78,400 B
    __shared__ __align__(16) float normA[SEQN];                   //  1,536 B
    __shared__ __align__(8)  float2 bring[320];                   //  2,560 B
    __shared__ int done[2][16];
    __shared__ int cons_prog[2];

    const int bat  = blockIdx.x;
    const int tid  = threadIdx.x;
    const int wv   = tid >> 6;
    const int lane = tid & 63;

    if (tid < 32) done[tid >> 4][tid & 15] = 0;
    if (tid == 32) cons_prog[0] = -1;
    if (tid == 33) cons_prog[1] = -1;
    __syncthreads();                       // only block-wide sync in the kernel

    if (wv >= 2) {
        // ========================= PRODUCERS (waves 2,3) =====================
        const int l16 = lane & 15, q = lane >> 4;
        const int sbase = (wv - 2) * 6;    // this wave's si-groups (of 12)
        const float* __restrict__ Bb = B + (long)bat * SEQM * DIM;

        // pad cols 384..387 -> dedicated slots 196..199 (written once, no gate)
        {
            unsigned short* ring = (wv == 2) ? ring0 : ring1;
            uint32_t pv = bf16_pair(KINF2, KINF2);
            int c = lane >> 4, i16 = lane & 15;          // 4 cols x 16 lanes
            uint32_t* p = (uint32_t*)&ring[(196 + c) * CSTR] + i16 * 6;
            #pragma unroll
            for (int j = 0; j < 6; j++) p[j] = pv;       // 96 dw = 192 ushorts
            if (lane == 0)
                __hip_atomic_store(&done[wv - 2][12], NPROD, __ATOMIC_RELEASE, WG);
        }

        // task list ordered by consumer deadline; (0,1) promoted for wave1 init
        const signed char TK[24] = {0,0,1,2,3,4,5,6,7,1,8,2,9,3,10,4,11,5,6,7,8,9,10,11};
        const signed char THh[24]= {0,1,0,0,0,0,0,0,0,1,0,1,0,1,0, 1,0, 1,1,1,1,1,1, 1};
        bool first0 = true, first1 = true;

        for (int ti = 0; ti < 24; ti++) {
            const int k  = TK[ti];
            const int hh = THh[ti];
            if (k >= 6) {
                // ring-wrap gate: task (k,hh) destroys cols <= 32k-165 of its
                // ring; owning consumer's last read of col C is at PHASE2
                // (C+121)/2 [h0] / (C+315)/2 [h1] -> thr 16k-22 / 16k+75, +2.
                int thr = hh ? (16 * k + 77) : (16 * k - 20);
                SPIN_GE(&cons_prog[hh], thr);
            }
            unsigned short* __restrict__ ring = hh ? ring1 : ring0;
            const float* __restrict__ Abh = A + ((long)bat * SEQN + 192 * hh) * DIM;
            const bool first = hh ? first1 : first0;

            // ---- B fragments for 32 cols (2 j-groups of 16) + b-norms ----
            frag_u bfrag[2][4];
            float bn[2];
            #pragma unroll
            for (int jg = 0; jg < 2; jg++) {
                const float* bp = Bb + (long)(32 * k + jg * 16 + l16) * DIM + q * 8;
                float s = 0.0f;
                #pragma unroll
                for (int kk = 0; kk < 4; kk++) {
                    float4 w0 = *(const float4*)(bp + kk * 32);
                    float4 w1 = *(const float4*)(bp + kk * 32 + 4);
                    bfrag[jg][kk].u[0] = bf16_pair(w0.x, w0.y);
                    bfrag[jg][kk].u[1] = bf16_pair(w0.z, w0.w);
                    bfrag[jg][kk].u[2] = bf16_pair(w1.x, w1.y);
                    bfrag[jg][kk].u[3] = bf16_pair(w1.z, w1.w);
                    s += w0.x*w0.x + w0.y*w0.y + w0.z*w0.z + w0.w*w0.w
                       + w1.x*w1.x + w1.y*w1.y + w1.z*w1.z + w1.w*w1.w;
                }
                s += __shfl_xor(s, 16, 64);
                s += __shfl_xor(s, 32, 64);
                bn[jg] = s;
            }
            // ---- this wave's 6 si-groups, 1-deep A prefetch ----
            float4 c0v[4], c1v[4];
            {
                const float* ap = Abh + (long)(sbase * 16 + l16) * DIM + q * 8;
                #pragma unroll
                for (int kk = 0; kk < 4; kk++) {
                    c0v[kk] = *(const float4*)(ap + kk * 32);
                    c1v[kk] = *(const float4*)(ap + kk * 32 + 4);
                }
            }
            #pragma unroll
            for (int s6 = 0; s6 < 6; s6++) {
                const int si = sbase + s6;
                float4 n0[4], n1[4];
                if (s6 < 5) {
                    const float* ap = Abh + (long)((si + 1) * 16 + l16) * DIM + q * 8;
                    #pragma unroll
                    for (int kk = 0; kk < 4; kk++) {
                        n0[kk] = *(const float4*)(ap + kk * 32);
                        n1[kk] = *(const float4*)(ap + kk * 32 + 4);
                    }
                }
                frag_u afr[4];
                #pragma unroll
                for (int kk = 0; kk < 4; kk++) {
                    afr[kk].u[0] = bf16_pair(c0v[kk].x, c0v[kk].y);
                    afr[kk].u[1] = bf16_pair(c0v[kk].z, c0v[kk].w);
                    afr[kk].u[2] = bf16_pair(c1v[kk].x, c1v[kk].y);
                    afr[kk].u[3] = bf16_pair(c1v[kk].z, c1v[kk].w);
                }
                if (first) {               // norms for this wave's rows, once/half
                    float sa = 0.0f;
                    #pragma unroll
                    for (int kk = 0; kk < 4; kk++)
                        sa += c0v[kk].x*c0v[kk].x + c0v[kk].y*c0v[kk].y
                            + c0v[kk].z*c0v[kk].z + c0v[kk].w*c0v[kk].w
                            + c1v[kk].x*c1v[kk].x + c1v[kk].y*c1v[kk].y
                            + c1v[kk].z*c1v[kk].z + c1v[kk].w*c1v[kk].w;
                    sa += __shfl_xor(sa, 16, 64);
                    sa += __shfl_xor(sa, 32, 64);
                    if (q == 0) normA[192 * hh + si * 16 + l16] = sa;
                }
                f32x4 acc0 = {0.0f, 0.0f, 0.0f, 0.0f};
                f32x4 acc1 = {0.0f, 0.0f, 0.0f, 0.0f};
                #pragma unroll
                for (int kk = 0; kk < 4; kk++) {
                    acc0 = __builtin_amdgcn_mfma_f32_16x16x32_bf16(
                               afr[kk].v, bfrag[0][kk].v, acc0, 0, 0, 0);
                    acc1 = __builtin_amdgcn_mfma_f32_16x16x32_bf16(
                               afr[kk].v, bfrag[1][kk].v, acc1, 0, 0, 0);
                }
                if (first) asm volatile("s_waitcnt lgkmcnt(0)" ::: "memory");
                float4 an = *(const float4*)&normA[192 * hh + si * 16 + q * 4];
                #pragma unroll
                for (int jg = 0; jg < 2; jg++) {
                    int col  = 32 * k + jg * 16 + l16;
                    int slot = col >= 196 ? col - 196 : col;
                    f32x4 ac = jg ? acc1 : acc0;
                    ushort4 pk;
                    pk.x = bf16_rne((an.x + bn[jg] - 2.0f * ac[0]) * LOG2E);
                    pk.y = bf16_rne((an.y + bn[jg] - 2.0f * ac[1]) * LOG2E);
                    pk.z = bf16_rne((an.z + bn[jg] - 2.0f * ac[2]) * LOG2E);
                    pk.w = bf16_rne((an.w + bn[jg] - 2.0f * ac[3]) * LOG2E);
                    *(ushort4*)&ring[slot * CSTR + si * 16 + q * 4] = pk;
                }
                if (s6 < 5) {
                    #pragma unroll
                    for (int kk = 0; kk < 4; kk++) { c0v[kk] = n0[kk]; c1v[kk] = n1[kk]; }
                }
            }
            if (hh) first1 = false; else first0 = false;
            if (lane == 0)
                __hip_atomic_fetch_add(&done[hh][k], 1, __ATOMIC_RELEASE, WG);
        }
        return;
    }

    // ================== CONSUMERS (waves 0,1): soft-DTW DP ===================
    const int  h     = wv;                 // 0: rows 0..191, 1: rows 192..383
    const int  t     = lane;
    const bool isl0  = (t == 0);
    const int  off   = h ? OFF1 : 0;
    const int  npair = h ? NPAIR1 : NPAIR0;
    const unsigned short* __restrict__ ringT = (h ? ring1 : ring0) + 3 * t;

    SPIN_GE(&done[h][0], NPROD);           // own half's chunk 0 (init reads)

    float prev[3];
    #pragma unroll
    for (int r = 0; r < 3; r++) prev[r] = KINF2;

    us3 dslot[4];                          // slot qq holds D column (c0 + qq)
    #pragma unroll
    for (int qq = 0; qq < 4; qq++) {
        int c = qq - 2 * t - off;
        int cc = c < 0 ? 0 : c;            // clamped cols < 196 here
        const unsigned short* p = ringT + cc * CSTR;
        dslot[qq].u[0] = p[0]; dslot[qq].u[1] = p[1]; dslot[qq].u[2] = p[2];
    }

    float rcv0 = KINF2, rcv1 = KINF2, old_diag = KINF2;
    float lane0_diag = h ? KINF2 : 0.0f;   // R[0][0] seed lives in wave0 only
    float b_rcv0 = KINF2, b_rcv1 = KINF2, b_old = KINF2;   // wave1 boundary regs
    float botA = KINF2, botB = KINF2;
    float2 bq0 = make_float2(KINF2, KINF2), bq1 = bq0;     // 2-deep bring FIFO
    int c0 = -2 * t - off;
    int kdone = 0, w0seen = -1;

#define UNPACK3(d, w)                                                       \
    d[0] = __uint_as_float(((uint32_t)w.u[0]) << 16);                       \
    d[1] = __uint_as_float(((uint32_t)w.u[1]) << 16);                       \
    d[2] = __uint_as_float(((uint32_t)w.u[2]) << 16);

#define COLPASS(dX, diag0, upseed, LEFTV, NEWV)                             \
    {                                                                       \
        float Bp = (upseed), Fp = 1.0f;                                     \
        float Bv[3], Fv[3];                                                 \
        _Pragma("unroll")                                                   \
        for (int r = 0; r < 3; r++) {                                       \
            float vd = (r == 0) ? (diag0) : LEFTV[r - 1];                   \
            float vl = LEFTV[r];                                            \
            float m3 = fminf(fminf(vd, vl), Bp);     /* v_min3_f32 */       \
            float al = EXP2F(m3 - Bp);                                      \
            float be = EXP2F(m3 - vd) + EXP2F(m3 - vl);                     \
            float Fr = __builtin_fmaf(al, Fp, be);                          \
            float Br = dX[r] + m3;                                          \
            Bv[r] = Br; Fv[r] = Fr;                                         \
            Bp = Br; Fp = Fr;                                               \
        }                                                                   \
        _Pragma("unroll")                                                   \
        for (int r = 0; r < 3; r++)                                         \
            NEWV[r] = Bv[r] - LOG2F(Fv[r]);                                 \
    }

#define PHASE2(Q)                                                           \
    {                                                                       \
        us3 wA = dslot[Q];                                                  \
        us3 wB = dslot[(Q) + 1];                                            \
        {   /* refill both slots for phase p+2 from this half's ring */     \
            int cnA = c0 + 4;                                               \
            int ccA = cnA < 0 ? 0 : (cnA > 387 ? 387 : cnA);                \
            int cnB = c0 + 5;                                               \
            int ccB = cnB < 0 ? 0 : (cnB > 387 ? 387 : cnB);                \
            int sA = ccA >= 384 ? ccA - 188 : (ccA >= 196 ? ccA - 196 : ccA); \
            int sB = ccB >= 384 ? ccB - 188 : (ccB >= 196 ? ccB - 196 : ccB); \
            const unsigned short* pA = ringT + sA * CSTR;                   \
            const unsigned short* pB = ringT + sB * CSTR;                   \
            dslot[Q].u[0]       = pA[0];                                    \
            dslot[Q].u[1]       = pA[1];                                    \
            dslot[Q].u[2]       = pA[2];                                    \
            dslot[(Q) + 1].u[0] = pB[0];                                    \
            dslot[(Q) + 1].u[1] = pB[1];                                    \
            dslot[(Q) + 1].u[2] = pB[2];                                    \
        }                                                                   \
        float dA[3], dB[3];                                                 \
        UNPACK3(dA, wA)                                                     \
        UNPACK3(dB, wB)                                                     \
        float dgA = isl0 ? (h ? b_old  : lane0_diag) : old_diag;            \
        float upA = isl0 ? (h ? b_rcv0 : KINF2)      : rcv0;                \
        float upB = isl0 ? (h ? b_rcv1 : KINF2)      : rcv1;                \
        float newA[3];                                                      \
        COLPASS(dA, dgA, upA, prev, newA)                                   \
        COLPASS(dB, upA, upB, newA, prev)                                   \
        old_diag = rcv1;                                                    \
        rcv0 = __shfl_up(newA[2], 1, 64);                                   \
        rcv1 = __shfl_up(prev[2], 1, 64);                                   \
        botA = newA[2]; botB = prev[2];                                     \
        lane0_diag = KINF2;                                                 \
        c0 += 2;                                                            \
    }

    // TAIL0 (wave0): bottom row -> bring[m] (non-wrapping), publish every 8.
#define TAIL0(m)                                                            \
    {                                                                       \
        if (t == 63) {                                                      \
            bring[m] = make_float2(botA, botB);                             \
            if (((m) & 7) == 7)                                             \
                __hip_atomic_store(&cons_prog[0], (m), __ATOMIC_RELEASE, WG); \
        }                                                                   \
    }
    // TAIL1 (wave1): consume slot n-33 via 2-deep FIFO; publish every 8.
#define TAIL1(n)                                                            \
    {                                                                       \
        b_old = b_rcv1;                                                     \
        if ((n) >= SLACK) { b_rcv0 = bq0.x; b_rcv1 = bq0.y; }               \
        else              { b_rcv0 = KINF2; b_rcv1 = KINF2; }               \
        bq0 = bq1;                                                          \
        int sl = (n) - 31;                                                  \
        if (sl >= 0) { if (sl > 319) sl = 319; bq1 = bring[sl]; }           \
        if (((n) & 7) == 7 && t == 63)                                      \
            __hip_atomic_store(&cons_prog[1], (n), __ATOMIC_RELEASE, WG);   \
    }

    for (int p = 0; p < npair; p++) {
        if ((p & 3) == 3) {
            // chunk gate: refills during pairs p..p+3 touch cols <= 4p+19-off
            int kr = (4 * p + 19 - off) >> 5;
            if (kr > 12) kr = 12;
            if (kr > kdone) { SPIN_GE(&done[h][kr], NPROD); kdone = kr; }
            if (h) {
                // bring availability: FIFO loads during pairs p..p+3 target
                // slots <= 2p+7-31 = 2p-24; wave0 publishes every 8.
                int thr = 2 * p - 24;
                if (thr > 319) thr = 319;
                if (thr >= 0 && w0seen < thr) {
                    int g = 0, v = w0seen;
                    do {
                        v = __hip_atomic_load(&cons_prog[0], __ATOMIC_ACQUIRE, WG);
                    } while (v < thr && ++g < (1 << 21));
                    w0seen = v;
                }
            }
        }
        PHASE2(0)
        if (h == 0) { TAIL0(2 * p) } else { TAIL1(2 * p) }
        PHASE2(2)
        if (h == 0) { TAIL0(2 * p + 1) } else { TAIL1(2 * p + 1) }
    }
#undef PHASE2
#undef COLPASS
#undef UNPACK3
#undef TAIL0
#undef TAIL1

    // wave1 lane63, last PHASE2 colB = D-col 383 (DP j=384): prev[2]=R[384][384]
    if (h == 1 && t == 63) out[bat] = prev[2] * LN2;
}

// ---------------------------------------------------------------------------
extern "C" void kernel_launch(void* const* d_in, const int* in_sizes, int n_in,
                              void* d_out, int out_size, void* d_ws, size_t ws_size,
                              hipStream_t stream) {
    (void)in_sizes; (void)n_in; (void)out_size; (void)d_ws; (void)ws_size;
    const float* a = (const float*)d_in[0];
    const float* b = (const float*)d_in[1];
    float* out = (float*)d_out;

    fused_dtw<<<dim3(BATCH), dim3(256), 0, stream>>>(a, b, out);
}

// Round 6
// 215.427 us; speedup vs baseline: 1.5647x; 1.0380x over previous
//
#include <hip/hip_runtime.h>
#include <stdint.h>

// Problem constants (fixed by the reference setup_inputs)
#define BATCH 128
#define SEQN  384
#define SEQM  384
#define DIM   128
#define KINF   1000000.0f                 // reference pseudo-infinity (nat units)
#define LOG2E  1.4426950408889634f
#define LN2    0.6931471805599453f
#define KINF2  (KINF * LOG2E)             // pseudo-infinity in base-2-scaled units

// Fused producer/consumer geometry (round-2 verified)
#define RING    204                       // LDS ring capacity in D-columns
#define RSTRIDE 392                       // ushorts per ring column (conflict-free banks)
#define NCHUNK  13                        // 0..11 = 32-col MFMA chunks; 12 = pad cols 384..387

// hardware base-2 transcendentals (v_exp_f32 / v_log_f32)
#define EXP2F(x) __builtin_amdgcn_exp2f(x)
#define LOG2F(x) __builtin_amdgcn_logf(x)

typedef __attribute__((ext_vector_type(8))) short bf16x8;   // 8 bf16 = 4 VGPRs (MFMA A/B frag)
typedef __attribute__((ext_vector_type(4))) float f32x4;    // MFMA C/D frag

__device__ __forceinline__ unsigned short bf16_rne(float x) {
    uint32_t u = __float_as_uint(x);
    u += 0x7FFFu + ((u >> 16) & 1u);
    return (unsigned short)(u >> 16);
}
__device__ __forceinline__ uint32_t bf16_pair(float x, float y) {
    uint32_t ux = __float_as_uint(x); ux += 0x7FFFu + ((ux >> 16) & 1u);
    uint32_t uy = __float_as_uint(y); uy += 0x7FFFu + ((uy >> 16) & 1u);
    return (ux >> 16) | (uy & 0xFFFF0000u);
}

union frag_u { bf16x8 v; uint32_t u[4]; };

// ---------------------------------------------------------------------------
// Fused kernel: one block per batch, 4 waves, 1 block/CU (round-2 topology).
//   wave 0   : soft-DTW DP consumer. NEW: the per-cell softmin carries the
//              exact pair v = B - log2(F):
//                m  = min3(B_up, B_diag, B_left)          (pure-VALU chain)
//                F' = exp2(m-B_up)F_up + exp2(m-B_dg)F_dg + exp2(m-B_lf)F_lf
//                B' = d + m;  then normalize F' by its exponent (bit-ops,
//                e folded into stored B) -> F in [1,2), e in [0,5].
//              Exact base-2 logsumexp identity; NO log2 anywhere in the
//              recurrence (one log2 per batch at the output). The serial
//              chain is min3+add only; exp2/fma hang off it with slack.
//   waves 1-3: producers, round-2 verbatim. Chunk k = D cols [32k,32k+32):
//              B-frags from global, 8 si-groups/wave (1-deep A prefetch),
//              MFMA, bf16 -> ring[col % 204]. Ring-wrap gate thr = 8k-12.
// ---------------------------------------------------------------------------
__global__ __launch_bounds__(256) void fused_dtw(
        const float* __restrict__ A, const float* __restrict__ B,
        float* __restrict__ out) {
    __shared__ __align__(16) unsigned short ring[RING * RSTRIDE]; // 159,936 B
    __shared__ __align__(16) float normA[SEQN];                   //   1,536 B
    __shared__ int prod_done[16];
    __shared__ int cons_pp;

    const int bat  = blockIdx.x;
    const int tid  = threadIdx.x;
    const int wv   = tid >> 6;
    const int lane = tid & 63;

    if (tid < 16) prod_done[tid] = 0;
    if (tid == 16) cons_pp = -1;
    __syncthreads();                       // only block-wide sync in the kernel

    if (wv != 0) {
        // ========================= PRODUCERS (waves 1..3) ====================
        const int l16 = lane & 15, q = lane >> 4;
        const int sbase = (wv - 1) * 8;    // this wave's si-groups: sbase..sbase+7
        const float* __restrict__ Ab = A + (long)bat * SEQN * DIM;
        const float* __restrict__ Bb = B + (long)bat * SEQM * DIM;
        bool first = true;
        for (int k = 0; k < NCHUNK; k++) {
            if (k >= 6) {
                // ring-wrap safety (round-2 derivation): thr = 8k-12.
                int thr = 8 * k - 12, g = 0;
                while (__hip_atomic_load(&cons_pp, __ATOMIC_ACQUIRE,
                                         __HIP_MEMORY_SCOPE_WORKGROUP) < thr)
                    if (++g > (1 << 22)) break;
            }
            if (k == 12) {
                if (wv == 1) {
                    uint32_t pv = bf16_pair(KINF2, KINF2);
                    #pragma unroll
                    for (int c = 0; c < 4; c++) {
                        uint32_t* p = (uint32_t*)&ring[(384 - RING + c) * RSTRIDE + 6 * lane];
                        p[0] = pv; p[1] = pv; p[2] = pv;
                    }
                }
            } else {
                frag_u bfrag[2][4];
                float bn[2];
                #pragma unroll
                for (int jg = 0; jg < 2; jg++) {
                    const float* bp = Bb + (long)(32 * k + jg * 16 + l16) * DIM + q * 8;
                    float s = 0.0f;
                    #pragma unroll
                    for (int kk = 0; kk < 4; kk++) {
                        float4 v0 = *(const float4*)(bp + kk * 32);
                        float4 v1 = *(const float4*)(bp + kk * 32 + 4);
                        bfrag[jg][kk].u[0] = bf16_pair(v0.x, v0.y);
                        bfrag[jg][kk].u[1] = bf16_pair(v0.z, v0.w);
                        bfrag[jg][kk].u[2] = bf16_pair(v1.x, v1.y);
                        bfrag[jg][kk].u[3] = bf16_pair(v1.z, v1.w);
                        s += v0.x*v0.x + v0.y*v0.y + v0.z*v0.z + v0.w*v0.w
                           + v1.x*v1.x + v1.y*v1.y + v1.z*v1.z + v1.w*v1.w;
                    }
                    s += __shfl_xor(s, 16, 64);
                    s += __shfl_xor(s, 32, 64);
                    bn[jg] = s;
                }
                float4 c0v[4], c1v[4];
                {
                    const float* ap = Ab + (long)(sbase * 16 + l16) * DIM + q * 8;
                    #pragma unroll
                    for (int kk = 0; kk < 4; kk++) {
                        c0v[kk] = *(const float4*)(ap + kk * 32);
                        c1v[kk] = *(const float4*)(ap + kk * 32 + 4);
                    }
                }
                #pragma unroll
                for (int s8 = 0; s8 < 8; s8++) {
                    const int si = sbase + s8;
                    float4 n0[4], n1[4];
                    if (s8 < 7) {
                        const float* ap = Ab + (long)((si + 1) * 16 + l16) * DIM + q * 8;
                        #pragma unroll
                        for (int kk = 0; kk < 4; kk++) {
                            n0[kk] = *(const float4*)(ap + kk * 32);
                            n1[kk] = *(const float4*)(ap + kk * 32 + 4);
                        }
                    }
                    frag_u afr[4];
                    #pragma unroll
                    for (int kk = 0; kk < 4; kk++) {
                        afr[kk].u[0] = bf16_pair(c0v[kk].x, c0v[kk].y);
                        afr[kk].u[1] = bf16_pair(c0v[kk].z, c0v[kk].w);
                        afr[kk].u[2] = bf16_pair(c1v[kk].x, c1v[kk].y);
                        afr[kk].u[3] = bf16_pair(c1v[kk].z, c1v[kk].w);
                    }
                    if (first) {
                        float sa = 0.0f;
                        #pragma unroll
                        for (int kk = 0; kk < 4; kk++)
                            sa += c0v[kk].x*c0v[kk].x + c0v[kk].y*c0v[kk].y
                                + c0v[kk].z*c0v[kk].z + c0v[kk].w*c0v[kk].w
                                + c1v[kk].x*c1v[kk].x + c1v[kk].y*c1v[kk].y
                                + c1v[kk].z*c1v[kk].z + c1v[kk].w*c1v[kk].w;
                        sa += __shfl_xor(sa, 16, 64);
                        sa += __shfl_xor(sa, 32, 64);
                        if (q == 0) normA[si * 16 + l16] = sa;
                    }
                    f32x4 acc0 = {0.0f, 0.0f, 0.0f, 0.0f};
                    f32x4 acc1 = {0.0f, 0.0f, 0.0f, 0.0f};
                    #pragma unroll
                    for (int kk = 0; kk < 4; kk++) {
                        acc0 = __builtin_amdgcn_mfma_f32_16x16x32_bf16(
                                   afr[kk].v, bfrag[0][kk].v, acc0, 0, 0, 0);
                        acc1 = __builtin_amdgcn_mfma_f32_16x16x32_bf16(
                                   afr[kk].v, bfrag[1][kk].v, acc1, 0, 0, 0);
                    }
                    if (first) asm volatile("s_waitcnt lgkmcnt(0)" ::: "memory");
                    float4 an = *(const float4*)&normA[si * 16 + q * 4];
                    #pragma unroll
                    for (int jg = 0; jg < 2; jg++) {
                        int col  = 32 * k + jg * 16 + l16;
                        int slot = col >= RING ? col - RING : col;
                        f32x4 ac = jg ? acc1 : acc0;
                        ushort4 pk;
                        pk.x = bf16_rne((an.x + bn[jg] - 2.0f * ac[0]) * LOG2E);
                        pk.y = bf16_rne((an.y + bn[jg] - 2.0f * ac[1]) * LOG2E);
                        pk.z = bf16_rne((an.z + bn[jg] - 2.0f * ac[2]) * LOG2E);
                        pk.w = bf16_rne((an.w + bn[jg] - 2.0f * ac[3]) * LOG2E);
                        *(ushort4*)&ring[slot * RSTRIDE + si * 16 + q * 4] = pk;
                    }
                    if (s8 < 7) {
                        #pragma unroll
                        for (int kk = 0; kk < 4; kk++) { c0v[kk] = n0[kk]; c1v[kk] = n1[kk]; }
                    }
                }
                first = false;
            }
            if (lane == 0)   // lane-0 only: counter==3 truly means all 3 waves
                __hip_atomic_fetch_add(&prod_done[k], 1, __ATOMIC_RELEASE,
                                       __HIP_MEMORY_SCOPE_WORKGROUP);
        }
        return;
    }

    // =========================== CONSUMER (wave 0) ===========================
    const int t = lane;
    {
        int g = 0;
        while (__hip_atomic_load(&prod_done[0], __ATOMIC_ACQUIRE,
                                 __HIP_MEMORY_SCOPE_WORKGROUP) < 3)
            if (++g > (1 << 22)) break;
    }
    const unsigned short* __restrict__ ringT = ring + 6 * t;

    // DP state as exact pairs: v = B - log2(F), F normalized to [1,2).
    float prevB[6], prevF[6];
    #pragma unroll
    for (int r = 0; r < 6; r++) { prevB[r] = KINF2; prevF[r] = 1.0f; }

    uint3 dslot[4];                        // slot qq holds D column (c0 + qq)
    #pragma unroll
    for (int qq = 0; qq < 4; qq++) {
        int c = qq - 2 * t;
        int cc = c < 0 ? 0 : c;
        dslot[qq] = *(const uint3*)(ringT + (long)cc * RSTRIDE);
    }

    float rcv0B = KINF2, rcv0F = 1.0f;
    float rcv1B = KINF2, rcv1F = 1.0f;
    float odB   = KINF2, odF   = 1.0f;
    float l0dB  = 0.0f,  l0dF  = 1.0f;     // R[0][0]; (KINF2,1) afterwards
    const bool isl0 = (t == 0);
    int c0 = -2 * t;

#define UNPACK(d, w)                                                        \
    d[0] = __uint_as_float(w.x << 16);                                      \
    d[1] = __uint_as_float(w.x & 0xFFFF0000u);                              \
    d[2] = __uint_as_float(w.y << 16);                                      \
    d[3] = __uint_as_float(w.y & 0xFFFF0000u);                              \
    d[4] = __uint_as_float(w.z << 16);                                      \
    d[5] = __uint_as_float(w.z & 0xFFFF0000u);

    // Pair-domain softmin column pass. Chain is min3+add (pure VALU); the
    // up-chain (Bp,Fp) runs unnormalized within the column (F <= ~26, no
    // overflow); stores are exponent-normalized via bit-ops (no trans).
#define COLPASS(dX, dgB_, dgF_, upB_, upF_, LB, LF, NB, NF)                 \
    {                                                                       \
        float Bp = (upB_), Fp = (upF_);                                     \
        _Pragma("unroll")                                                   \
        for (int r = 0; r < 6; r++) {                                       \
            float vdB = (r == 0) ? (dgB_) : LB[r - 1];                      \
            float vdF = (r == 0) ? (dgF_) : LF[r - 1];                      \
            float vlB = LB[r], vlF = LF[r];                                 \
            float m3 = fminf(fminf(vdB, vlB), Bp);   /* v_min3_f32 */       \
            float Fr = EXP2F(m3 - Bp) * Fp;                                 \
            Fr = __builtin_fmaf(EXP2F(m3 - vdB), vdF, Fr);                  \
            Fr = __builtin_fmaf(EXP2F(m3 - vlB), vlF, Fr);                  \
            float Br = dX[r] + m3;                                          \
            uint32_t fb = __float_as_uint(Fr);                              \
            int e = (int)(fb >> 23) - 127;                                  \
            NB[r] = Br - (float)e;                                          \
            NF[r] = __uint_as_float((fb & 0x007FFFFFu) | 0x3F800000u);      \
            Bp = Br; Fp = Fr;      /* unnormalized within the column */     \
        }                                                                   \
    }

#define PHASE2(Q)                                                           \
    {                                                                       \
        uint3 wA = dslot[Q];                                                \
        uint3 wB = dslot[(Q) + 1];                                          \
        {   /* refill both slots for phase p+2 from the LDS ring */         \
            int cnA = c0 + 4;                                               \
            int ccA = cnA < 0 ? 0 : (cnA > 387 ? 387 : cnA);                \
            int sA  = ccA >= RING ? ccA - RING : ccA;                       \
            int cnB = c0 + 5;                                               \
            int ccB = cnB < 0 ? 0 : (cnB > 387 ? 387 : cnB);                \
            int sB  = ccB >= RING ? ccB - RING : ccB;                       \
            dslot[Q]       = *(const uint3*)(ringT + (long)sA * RSTRIDE);   \
            dslot[(Q) + 1] = *(const uint3*)(ringT + (long)sB * RSTRIDE);   \
        }                                                                   \
        float dA[6], dB6[6];                                                \
        UNPACK(dA, wA)                                                      \
        UNPACK(dB6, wB)                                                     \
        float dgAB = isl0 ? l0dB : odB;                                     \
        float dgAF = isl0 ? l0dF : odF;                                     \
        float upAB = isl0 ? KINF2 : rcv0B;                                  \
        float upAF = isl0 ? 1.0f  : rcv0F;                                  \
        float upBB = isl0 ? KINF2 : rcv1B;                                  \
        float upBF = isl0 ? 1.0f  : rcv1F;                                  \
        float nAB[6], nAF[6];                                               \
        COLPASS(dA,  dgAB, dgAF, upAB, upAF, prevB, prevF, nAB, nAF)        \
        COLPASS(dB6, upAB, upAF, upBB, upBF, nAB, nAF, prevB, prevF)        \
        odB = rcv1B; odF = rcv1F;                                           \
        rcv0B = __shfl_up(nAB[5],   1, 64);                                 \
        rcv0F = __shfl_up(nAF[5],   1, 64);                                 \
        rcv1B = __shfl_up(prevB[5], 1, 64);                                 \
        rcv1F = __shfl_up(prevF[5], 1, 64);                                 \
        l0dB = KINF2; l0dF = 1.0f;                                          \
        c0 += 2;                                                            \
    }

    for (int pp = 0; pp < 127; pp++) {               // phase pairs 0..126
        if ((pp & 7) == 7) {                         // gate chunk k (round-2)
            int k = (4 * pp + 7) >> 5;
            if (k < NCHUNK) {
                int g = 0;
                while (__hip_atomic_load(&prod_done[k], __ATOMIC_ACQUIRE,
                                         __HIP_MEMORY_SCOPE_WORKGROUP) < 3)
                    if (++g > (1 << 22)) break;
            }
        }
        PHASE2(0)
        PHASE2(2)
        if (t == 0)                                  // publish progress (release)
            __hip_atomic_store(&cons_pp, pp,
                               __ATOMIC_RELEASE, __HIP_MEMORY_SCOPE_WORKGROUP);
    }
    PHASE2(0)                                        // phase 254
#undef PHASE2
#undef COLPASS
#undef UNPACK

    // lane 63, last phase colB = column 384: (prevB,prevF)[5] = R[384][384]
    if (t == 63) out[bat] = (prevB[5] - LOG2F(prevF[5])) * LN2;
}

// ---------------------------------------------------------------------------
extern "C" void kernel_launch(void* const* d_in, const int* in_sizes, int n_in,
                              void* d_out, int out_size, void* d_ws, size_t ws_size,
                              hipStream_t stream) {
    (void)in_sizes; (void)n_in; (void)out_size; (void)d_ws; (void)ws_size;
    const float* a = (const float*)d_in[0];
    const float* b = (const float*)d_in[1];
    float* out = (float*)d_out;

    fused_dtw<<<dim3(BATCH), dim3(256), 0, stream>>>(a, b, out);
}

// Round 8
// 199.065 us; speedup vs baseline: 1.6933x; 1.0822x over previous
//
#include <hip/hip_runtime.h>
#include <stdint.h>

// Problem constants (fixed by the reference setup_inputs)
#define BATCH 128
#define SEQN  384
#define SEQM  384
#define DIM   128
#define KINF   1000000.0f                 // reference pseudo-infinity (nat units)
#define LOG2E  1.4426950408889634f
#define LN2    0.6931471805599453f
#define KINF2  (KINF * LOG2E)             // pseudo-infinity in base-2-scaled units

// Fused producer/consumer geometry (round-2 verified)
#define RING    204                       // LDS ring capacity in D-columns
#define RSTRIDE 392                       // ushorts per ring column (conflict-free banks)

// hardware base-2 transcendentals (v_exp_f32 / v_log_f32)
#define EXP2F(x) __builtin_amdgcn_exp2f(x)
#define LOG2F(x) __builtin_amdgcn_logf(x)

#define WG __HIP_MEMORY_SCOPE_WORKGROUP

typedef __attribute__((ext_vector_type(8))) short bf16x8;   // 8 bf16 = 4 VGPRs (MFMA A/B frag)
typedef __attribute__((ext_vector_type(4))) float f32x4;    // MFMA C/D frag

__device__ __forceinline__ unsigned short bf16_rne(float x) {
    uint32_t u = __float_as_uint(x);
    u += 0x7FFFu + ((u >> 16) & 1u);
    return (unsigned short)(u >> 16);
}
__device__ __forceinline__ uint32_t bf16_pair(float x, float y) {
    uint32_t ux = __float_as_uint(x); ux += 0x7FFFu + ((ux >> 16) & 1u);
    uint32_t uy = __float_as_uint(y); uy += 0x7FFFu + ((uy >> 16) & 1u);
    return (ux >> 16) | (uy & 0xFFFF0000u);
}

union frag_u { bf16x8 v; uint32_t u[4]; };

// ---------------------------------------------------------------------------
// Fused kernel: one block per batch, 8 waves (512 thr), 1 block/CU.
//   wave 0          : soft-DTW DP consumer — round-2 v-domain body VERBATIM
//                     (fastest measured: exp-domain linear recurrence, serial
//                     chain = min3+add, log2 off-chain). s_setprio(1).
//   wave 4          : pad-column writer (cols 384..387 -> ring slots 180..183)
//                     — sleeps (s_sleep) until cons_pp >= 84, writes, exits.
//                     Shares SIMD0 with the consumer, so it must not spin hot.
//   waves 1-3,5-7   : 6 producers, pidx = {0,1,2,3,4,5}  [r7 BUGFIX: was
//                     (wv-3) for wv>=5, colliding 5 with 3 and leaving rows
//                     320..383 unproduced -> NaN]. Chunk k = D cols
//                     [32k,32k+32): B-frags from global + 4 si-groups/wave
//                     (1-deep A prefetch) + MFMA -> ring[col % 204].
// Ring-wrap gate thr = 8k-12 (round-2 derivation, producer-count independent).
// ---------------------------------------------------------------------------
__global__ __launch_bounds__(512) void fused_dtw(
        const float* __restrict__ A, const float* __restrict__ B,
        float* __restrict__ out) {
    __shared__ __align__(16) unsigned short ring[RING * RSTRIDE]; // 159,936 B
    __shared__ __align__(16) float normA[SEQN];                   //   1,536 B
    __shared__ int prod_done[16];
    __shared__ int cons_pp;

    const int bat  = blockIdx.x;
    const int tid  = threadIdx.x;
    const int wv   = tid >> 6;
    const int lane = tid & 63;

    if (tid < 16) prod_done[tid] = 0;
    if (tid == 16) cons_pp = -1;
    __syncthreads();                       // only block-wide sync in the kernel

    if (wv == 4) {
        // ================= PAD WRITER (wave 4, shares SIMD0) =================
        // cols 384..387 overwrite ring slots 180..183 (live as cols 180..183
        // until the consumer passes pp ~77); gate cons_pp >= 84 (r2-verified).
        int g = 0;
        while (__hip_atomic_load(&cons_pp, __ATOMIC_ACQUIRE, WG) < 84) {
            __builtin_amdgcn_s_sleep(8);   // ~512 cyc naps: no issue pressure
            if (++g > (1 << 20)) break;
        }
        uint32_t pv = bf16_pair(KINF2, KINF2);
        #pragma unroll
        for (int c = 0; c < 4; c++) {
            uint32_t* p = (uint32_t*)&ring[(384 - RING + c) * RSTRIDE + 6 * lane];
            p[0] = pv; p[1] = pv; p[2] = pv;
        }
        if (lane == 0)
            __hip_atomic_fetch_add(&prod_done[12], 6, __ATOMIC_RELEASE, WG);
        return;
    }

    if (wv != 0) {
        // ============== PRODUCERS (waves 1,2,3,5,6,7 -> pidx 0..5) ===========
        const int pidx  = (wv < 4) ? (wv - 1) : (wv - 2);   // r7 BUGFIX
        const int sbase = pidx * 4;        // this wave's 4 si-groups (of 24)
        const int l16 = lane & 15, q = lane >> 4;
        const float* __restrict__ Ab = A + (long)bat * SEQN * DIM;
        const float* __restrict__ Bb = B + (long)bat * SEQM * DIM;
        bool first = true;
        for (int k = 0; k < 12; k++) {
            if (k >= 6) {
                // ring-wrap safety (round-2 derivation): thr = 8k-12.
                int thr = 8 * k - 12, g = 0;
                while (__hip_atomic_load(&cons_pp, __ATOMIC_ACQUIRE, WG) < thr) {
                    __builtin_amdgcn_s_sleep(2);
                    if (++g > (1 << 21)) break;
                }
            }
            // ---- B fragments for 32 cols (2 j-groups of 16) + b-norms ----
            frag_u bfrag[2][4];
            float bn[2];
            #pragma unroll
            for (int jg = 0; jg < 2; jg++) {
                const float* bp = Bb + (long)(32 * k + jg * 16 + l16) * DIM + q * 8;
                float s = 0.0f;
                #pragma unroll
                for (int kk = 0; kk < 4; kk++) {
                    float4 v0 = *(const float4*)(bp + kk * 32);
                    float4 v1 = *(const float4*)(bp + kk * 32 + 4);
                    bfrag[jg][kk].u[0] = bf16_pair(v0.x, v0.y);
                    bfrag[jg][kk].u[1] = bf16_pair(v0.z, v0.w);
                    bfrag[jg][kk].u[2] = bf16_pair(v1.x, v1.y);
                    bfrag[jg][kk].u[3] = bf16_pair(v1.z, v1.w);
                    s += v0.x*v0.x + v0.y*v0.y + v0.z*v0.z + v0.w*v0.w
                       + v1.x*v1.x + v1.y*v1.y + v1.z*v1.z + v1.w*v1.w;
                }
                s += __shfl_xor(s, 16, 64);
                s += __shfl_xor(s, 32, 64);
                bn[jg] = s;                // norm of this lane's j row
            }
            // ---- this wave's 4 si-groups, 1-deep A prefetch ----
            float4 c0v[4], c1v[4];
            {
                const float* ap = Ab + (long)(sbase * 16 + l16) * DIM + q * 8;
                #pragma unroll
                for (int kk = 0; kk < 4; kk++) {
                    c0v[kk] = *(const float4*)(ap + kk * 32);
                    c1v[kk] = *(const float4*)(ap + kk * 32 + 4);
                }
            }
            #pragma unroll
            for (int s4 = 0; s4 < 4; s4++) {
                const int si = sbase + s4;
                float4 n0[4], n1[4];
                if (s4 < 3) {              // prefetch next si-group
                    const float* ap = Ab + (long)((si + 1) * 16 + l16) * DIM + q * 8;
                    #pragma unroll
                    for (int kk = 0; kk < 4; kk++) {
                        n0[kk] = *(const float4*)(ap + kk * 32);
                        n1[kk] = *(const float4*)(ap + kk * 32 + 4);
                    }
                }
                frag_u afr[4];
                #pragma unroll
                for (int kk = 0; kk < 4; kk++) {
                    afr[kk].u[0] = bf16_pair(c0v[kk].x, c0v[kk].y);
                    afr[kk].u[1] = bf16_pair(c0v[kk].z, c0v[kk].w);
                    afr[kk].u[2] = bf16_pair(c1v[kk].x, c1v[kk].y);
                    afr[kk].u[3] = bf16_pair(c1v[kk].z, c1v[kk].w);
                }
                if (first) {               // this wave's normA slice (own rows)
                    float sa = 0.0f;
                    #pragma unroll
                    for (int kk = 0; kk < 4; kk++)
                        sa += c0v[kk].x*c0v[kk].x + c0v[kk].y*c0v[kk].y
                            + c0v[kk].z*c0v[kk].z + c0v[kk].w*c0v[kk].w
                            + c1v[kk].x*c1v[kk].x + c1v[kk].y*c1v[kk].y
                            + c1v[kk].z*c1v[kk].z + c1v[kk].w*c1v[kk].w;
                    sa += __shfl_xor(sa, 16, 64);
                    sa += __shfl_xor(sa, 32, 64);
                    if (q == 0) normA[si * 16 + l16] = sa;
                }
                f32x4 acc0 = {0.0f, 0.0f, 0.0f, 0.0f};
                f32x4 acc1 = {0.0f, 0.0f, 0.0f, 0.0f};
                #pragma unroll
                for (int kk = 0; kk < 4; kk++) {
                    acc0 = __builtin_amdgcn_mfma_f32_16x16x32_bf16(
                               afr[kk].v, bfrag[0][kk].v, acc0, 0, 0, 0);
                    acc1 = __builtin_amdgcn_mfma_f32_16x16x32_bf16(
                               afr[kk].v, bfrag[1][kk].v, acc1, 0, 0, 0);
                }
                if (first) asm volatile("s_waitcnt lgkmcnt(0)" ::: "memory");
                float4 an = *(const float4*)&normA[si * 16 + q * 4];
                #pragma unroll
                for (int jg = 0; jg < 2; jg++) {
                    int col  = 32 * k + jg * 16 + l16;
                    int slot = col >= RING ? col - RING : col;
                    f32x4 ac = jg ? acc1 : acc0;
                    ushort4 pk;
                    pk.x = bf16_rne((an.x + bn[jg] - 2.0f * ac[0]) * LOG2E);
                    pk.y = bf16_rne((an.y + bn[jg] - 2.0f * ac[1]) * LOG2E);
                    pk.z = bf16_rne((an.z + bn[jg] - 2.0f * ac[2]) * LOG2E);
                    pk.w = bf16_rne((an.w + bn[jg] - 2.0f * ac[3]) * LOG2E);
                    *(ushort4*)&ring[slot * RSTRIDE + si * 16 + q * 4] = pk;
                }
                if (s4 < 3) {
                    #pragma unroll
                    for (int kk = 0; kk < 4; kk++) { c0v[kk] = n0[kk]; c1v[kk] = n1[kk]; }
                }
            }
            first = false;
            if (lane == 0)   // lane-0 only: counter==6 truly means all 6 waves
                __hip_atomic_fetch_add(&prod_done[k], 1, __ATOMIC_RELEASE, WG);
        }
        return;
    }

    // ============ CONSUMER (wave 0): round-2 v-domain body, verbatim =========
    const int t = lane;
    {
        int g = 0;
        while (__hip_atomic_load(&prod_done[0], __ATOMIC_ACQUIRE, WG) < 6)
            if (++g > (1 << 22)) break;
    }
    __builtin_amdgcn_s_setprio(1);         // favor the DP wave on its SIMD (T5)
    const unsigned short* __restrict__ ringT = ring + 6 * t;

    float prev[6];                                   // prev column's v (exact)
    #pragma unroll
    for (int r = 0; r < 6; r++) prev[r] = KINF2;

    // raw D FIFO: slot qq holds D column (c0 + qq)
    uint3 dslot[4];
    #pragma unroll
    for (int qq = 0; qq < 4; qq++) {
        int c = qq - 2 * t;
        int cc = c < 0 ? 0 : c;                      // clamp low (< RING always)
        dslot[qq] = *(const uint3*)(ringT + (long)cc * RSTRIDE);
    }

    float rcv0 = KINF2, rcv1 = KINF2, old_diag = KINF2;
    float lane0_diag = 0.0f;                         // R[0][0]; KINF2 afterwards
    const bool isl0 = (t == 0);
    int c0 = -2 * t;                                 // D-col of this phase's colA

#define UNPACK(d, w)                                                        \
    d[0] = __uint_as_float(w.x << 16);                                      \
    d[1] = __uint_as_float(w.x & 0xFFFF0000u);                              \
    d[2] = __uint_as_float(w.y << 16);                                      \
    d[3] = __uint_as_float(w.y & 0xFFFF0000u);                              \
    d[4] = __uint_as_float(w.z << 16);                                      \
    d[5] = __uint_as_float(w.z & 0xFFFF0000u);

#define COLPASS(dX, diag0, upseed, LEFTV, NEWV)                             \
    {                                                                       \
        float Bp = (upseed), Fp = 1.0f;                                     \
        float Bv[6], Fv[6];                                                 \
        _Pragma("unroll")                                                   \
        for (int r = 0; r < 6; r++) {                                       \
            float vd = (r == 0) ? (diag0) : LEFTV[r - 1];                   \
            float vl = LEFTV[r];                                            \
            float m3 = fminf(fminf(vd, vl), Bp);     /* v_min3_f32 */       \
            float al = EXP2F(m3 - Bp);                                      \
            float be = EXP2F(m3 - vd) + EXP2F(m3 - vl);                     \
            float Fr = __builtin_fmaf(al, Fp, be);                          \
            float Br = dX[r] + m3;                                          \
            Bv[r] = Br; Fv[r] = Fr;                                         \
            Bp = Br; Fp = Fr;                                               \
        }                                                                   \
        _Pragma("unroll")                                                   \
        for (int r = 0; r < 6; r++)                                         \
            NEWV[r] = Bv[r] - LOG2F(Fv[r]);                                 \
    }

#define PHASE2(Q)                                                           \
    {                                                                       \
        uint3 wA = dslot[Q];                                                \
        uint3 wB = dslot[(Q) + 1];                                          \
        {   /* refill both slots for phase p+2 from the LDS ring */         \
            int cnA = c0 + 4;                                               \
            int ccA = cnA < 0 ? 0 : (cnA > 387 ? 387 : cnA);                \
            int sA  = ccA >= RING ? ccA - RING : ccA;                       \
            int cnB = c0 + 5;                                               \
            int ccB = cnB < 0 ? 0 : (cnB > 387 ? 387 : cnB);                \
            int sB  = ccB >= RING ? ccB - RING : ccB;                       \
            dslot[Q]       = *(const uint3*)(ringT + (long)sA * RSTRIDE);   \
            dslot[(Q) + 1] = *(const uint3*)(ringT + (long)sB * RSTRIDE);   \
        }                                                                   \
        float dA[6], dB[6];                                                 \
        UNPACK(dA, wA)                                                      \
        UNPACK(dB, wB)                                                      \
        float dgA = isl0 ? lane0_diag : old_diag;                           \
        float upA = isl0 ? KINF2 : rcv0;                                    \
        float upB = isl0 ? KINF2 : rcv1;                                    \
        float newA[6];                                                      \
        COLPASS(dA, dgA, upA, prev, newA)                                   \
        COLPASS(dB, upA, upB, newA, prev)                                   \
        old_diag = rcv1;                                                    \
        rcv0 = __shfl_up(newA[5], 1, 64);                                   \
        rcv1 = __shfl_up(prev[5], 1, 64);                                   \
        lane0_diag = KINF2;                                                 \
        c0 += 2;                                                            \
    }

    for (int pp = 0; pp < 127; pp++) {               // phase pairs 0..126
        if ((pp & 7) == 7) {                         // gate chunk k (round-2)
            int k = (4 * pp + 7) >> 5;
            if (k < 13) {
                int g = 0;
                while (__hip_atomic_load(&prod_done[k], __ATOMIC_ACQUIRE, WG) < 6)
                    if (++g > (1 << 22)) break;
            }
        }
        PHASE2(0)
        PHASE2(2)
        if (t == 0)                                  // publish progress (release)
            __hip_atomic_store(&cons_pp, pp, __ATOMIC_RELEASE, WG);
    }
    PHASE2(0)                                        // phase 254
#undef PHASE2
#undef COLPASS
#undef UNPACK

    // lane 63, last phase colB = column 384: prev[5] = R[384][384]
    if (t == 63) out[bat] = prev[5] * LN2;
}

// ---------------------------------------------------------------------------
extern "C" void kernel_launch(void* const* d_in, const int* in_sizes, int n_in,
                              void* d_out, int out_size, void* d_ws, size_t ws_size,
                              hipStream_t stream) {
    (void)in_sizes; (void)n_in; (void)out_size; (void)d_ws; (void)ws_size;
    const float* a = (const float*)d_in[0];
    const float* b = (const float*)d_in[1];
    float* out = (float*)d_out;

    fused_dtw<<<dim3(BATCH), dim3(512), 0, stream>>>(a, b, out);
}

// Round 9
// 186.945 us; speedup vs baseline: 1.8031x; 1.0648x over previous
//
#include <hip/hip_runtime.h>
#include <stdint.h>

// Problem constants (fixed by the reference setup_inputs)
#define BATCH 128
#define SEQN  384
#define SEQM  384
#define DIM   128
#define KINF   1000000.0f                 // reference pseudo-infinity (nat units)
#define LOG2E  1.4426950408889634f
#define LN2    0.6931471805599453f
#define KINF2  (KINF * LOG2E)             // pseudo-infinity in base-2-scaled units

// Fused producer/consumer geometry
#define RING    204                       // LDS ring capacity in D-columns
#define RSTRIDE 392                       // ushorts per ring column (conflict-free banks)

// hardware base-2 transcendentals (v_exp_f32 / v_log_f32)
#define EXP2F(x) __builtin_amdgcn_exp2f(x)
#define LOG2F(x) __builtin_amdgcn_logf(x)

#define WG __HIP_MEMORY_SCOPE_WORKGROUP

typedef __attribute__((ext_vector_type(8))) short bf16x8;   // 8 bf16 = 4 VGPRs (MFMA A/B frag)
typedef __attribute__((ext_vector_type(4))) float f32x4;    // MFMA C/D frag

__device__ __forceinline__ unsigned short bf16_rne(float x) {
    uint32_t u = __float_as_uint(x);
    u += 0x7FFFu + ((u >> 16) & 1u);
    return (unsigned short)(u >> 16);
}
__device__ __forceinline__ uint32_t bf16_pair(float x, float y) {
    uint32_t ux = __float_as_uint(x); ux += 0x7FFFu + ((ux >> 16) & 1u);
    uint32_t uy = __float_as_uint(y); uy += 0x7FFFu + ((uy >> 16) & 1u);
    return (ux >> 16) | (uy & 0xFFFF0000u);
}

union frag_u { bf16x8 v; uint32_t u[4]; };

// ---------------------------------------------------------------------------
// Fused kernel: one block per batch, 8 waves (512 thr), 1 block/CU.
//   wave 0        : soft-DTW DP consumer. NEW vs r8: 1-column-per-lane skew
//                   (was 2/lane) -> 447 column-slots instead of 510 (-12.4%),
//                   same per-column cost (1 refill, 1 shfl, 6 cells). Progress
//                   published every 8 slots (was every pp) -> 1/4 the
//                   release-lgkm drains. Per-cell math (COLPASS) verbatim.
//   wave 4        : pad-column writer (cols 384..387 -> ring slots 180..183),
//                   sleeps until cons_sl >= 248 (slot units; last real read of
//                   col 183 is at slot 242), writes, exits.
//   waves 1-3,5-7 : 6 producers (pidx 0..5), r8-verbatim chunk pipeline.
//                   Ring-wrap gate in slot units: cons_sl >= 32k-110 (chunk k
//                   destroys cols <= 32k+31-204; last read of col C at slot
//                   C+59; +3 margin).
// ---------------------------------------------------------------------------
__global__ __launch_bounds__(512) void fused_dtw(
        const float* __restrict__ A, const float* __restrict__ B,
        float* __restrict__ out) {
    __shared__ __align__(16) unsigned short ring[RING * RSTRIDE]; // 159,936 B
    __shared__ __align__(16) float normA[SEQN];                   //   1,536 B
    __shared__ int prod_done[16];
    __shared__ int cons_sl;

    const int bat  = blockIdx.x;
    const int tid  = threadIdx.x;
    const int wv   = tid >> 6;
    const int lane = tid & 63;

    if (tid < 16) prod_done[tid] = 0;
    if (tid == 16) cons_sl = -1;
    __syncthreads();                       // only block-wide sync in the kernel

    if (wv == 4) {
        // ================= PAD WRITER (wave 4, shares SIMD0) =================
        // slots 180..183 hold cols 180..183 until consumer slot 242; gate 248.
        int g = 0;
        while (__hip_atomic_load(&cons_sl, __ATOMIC_ACQUIRE, WG) < 248) {
            __builtin_amdgcn_s_sleep(8);   // ~512 cyc naps: no issue pressure
            if (++g > (1 << 20)) break;
        }
        uint32_t pv = bf16_pair(KINF2, KINF2);
        #pragma unroll
        for (int c = 0; c < 4; c++) {
            uint32_t* p = (uint32_t*)&ring[(384 - RING + c) * RSTRIDE + 6 * lane];
            p[0] = pv; p[1] = pv; p[2] = pv;
        }
        if (lane == 0)
            __hip_atomic_fetch_add(&prod_done[12], 6, __ATOMIC_RELEASE, WG);
        return;
    }

    if (wv != 0) {
        // ============== PRODUCERS (waves 1,2,3,5,6,7 -> pidx 0..5) ===========
        const int pidx  = (wv < 4) ? (wv - 1) : (wv - 2);
        const int sbase = pidx * 4;        // this wave's 4 si-groups (of 24)
        const int l16 = lane & 15, q = lane >> 4;
        const float* __restrict__ Ab = A + (long)bat * SEQN * DIM;
        const float* __restrict__ Bb = B + (long)bat * SEQM * DIM;
        bool first = true;
        for (int k = 0; k < 12; k++) {
            if (k >= 6) {
                // ring-wrap safety, slot units: thr = 32k-110.
                int thr = 32 * k - 110, g = 0;
                while (__hip_atomic_load(&cons_sl, __ATOMIC_ACQUIRE, WG) < thr) {
                    __builtin_amdgcn_s_sleep(2);
                    if (++g > (1 << 21)) break;
                }
            }
            // ---- B fragments for 32 cols (2 j-groups of 16) + b-norms ----
            frag_u bfrag[2][4];
            float bn[2];
            #pragma unroll
            for (int jg = 0; jg < 2; jg++) {
                const float* bp = Bb + (long)(32 * k + jg * 16 + l16) * DIM + q * 8;
                float s = 0.0f;
                #pragma unroll
                for (int kk = 0; kk < 4; kk++) {
                    float4 v0 = *(const float4*)(bp + kk * 32);
                    float4 v1 = *(const float4*)(bp + kk * 32 + 4);
                    bfrag[jg][kk].u[0] = bf16_pair(v0.x, v0.y);
                    bfrag[jg][kk].u[1] = bf16_pair(v0.z, v0.w);
                    bfrag[jg][kk].u[2] = bf16_pair(v1.x, v1.y);
                    bfrag[jg][kk].u[3] = bf16_pair(v1.z, v1.w);
                    s += v0.x*v0.x + v0.y*v0.y + v0.z*v0.z + v0.w*v0.w
                       + v1.x*v1.x + v1.y*v1.y + v1.z*v1.z + v1.w*v1.w;
                }
                s += __shfl_xor(s, 16, 64);
                s += __shfl_xor(s, 32, 64);
                bn[jg] = s;                // norm of this lane's j row
            }
            // ---- this wave's 4 si-groups, 1-deep A prefetch ----
            float4 c0v[4], c1v[4];
            {
                const float* ap = Ab + (long)(sbase * 16 + l16) * DIM + q * 8;
                #pragma unroll
                for (int kk = 0; kk < 4; kk++) {
                    c0v[kk] = *(const float4*)(ap + kk * 32);
                    c1v[kk] = *(const float4*)(ap + kk * 32 + 4);
                }
            }
            #pragma unroll
            for (int s4 = 0; s4 < 4; s4++) {
                const int si = sbase + s4;
                float4 n0[4], n1[4];
                if (s4 < 3) {              // prefetch next si-group
                    const float* ap = Ab + (long)((si + 1) * 16 + l16) * DIM + q * 8;
                    #pragma unroll
                    for (int kk = 0; kk < 4; kk++) {
                        n0[kk] = *(const float4*)(ap + kk * 32);
                        n1[kk] = *(const float4*)(ap + kk * 32 + 4);
                    }
                }
                frag_u afr[4];
                #pragma unroll
                for (int kk = 0; kk < 4; kk++) {
                    afr[kk].u[0] = bf16_pair(c0v[kk].x, c0v[kk].y);
                    afr[kk].u[1] = bf16_pair(c0v[kk].z, c0v[kk].w);
                    afr[kk].u[2] = bf16_pair(c1v[kk].x, c1v[kk].y);
                    afr[kk].u[3] = bf16_pair(c1v[kk].z, c1v[kk].w);
                }
                if (first) {               // this wave's normA slice (own rows)
                    float sa = 0.0f;
                    #pragma unroll
                    for (int kk = 0; kk < 4; kk++)
                        sa += c0v[kk].x*c0v[kk].x + c0v[kk].y*c0v[kk].y
                            + c0v[kk].z*c0v[kk].z + c0v[kk].w*c0v[kk].w
                            + c1v[kk].x*c1v[kk].x + c1v[kk].y*c1v[kk].y
                            + c1v[kk].z*c1v[kk].z + c1v[kk].w*c1v[kk].w;
                    sa += __shfl_xor(sa, 16, 64);
                    sa += __shfl_xor(sa, 32, 64);
                    if (q == 0) normA[si * 16 + l16] = sa;
                }
                f32x4 acc0 = {0.0f, 0.0f, 0.0f, 0.0f};
                f32x4 acc1 = {0.0f, 0.0f, 0.0f, 0.0f};
                #pragma unroll
                for (int kk = 0; kk < 4; kk++) {
                    acc0 = __builtin_amdgcn_mfma_f32_16x16x32_bf16(
                               afr[kk].v, bfrag[0][kk].v, acc0, 0, 0, 0);
                    acc1 = __builtin_amdgcn_mfma_f32_16x16x32_bf16(
                               afr[kk].v, bfrag[1][kk].v, acc1, 0, 0, 0);
                }
                if (first) asm volatile("s_waitcnt lgkmcnt(0)" ::: "memory");
                float4 an = *(const float4*)&normA[si * 16 + q * 4];
                #pragma unroll
                for (int jg = 0; jg < 2; jg++) {
                    int col  = 32 * k + jg * 16 + l16;
                    int slot = col >= RING ? col - RING : col;
                    f32x4 ac = jg ? acc1 : acc0;
                    ushort4 pk;
                    pk.x = bf16_rne((an.x + bn[jg] - 2.0f * ac[0]) * LOG2E);
                    pk.y = bf16_rne((an.y + bn[jg] - 2.0f * ac[1]) * LOG2E);
                    pk.z = bf16_rne((an.z + bn[jg] - 2.0f * ac[2]) * LOG2E);
                    pk.w = bf16_rne((an.w + bn[jg] - 2.0f * ac[3]) * LOG2E);
                    *(ushort4*)&ring[slot * RSTRIDE + si * 16 + q * 4] = pk;
                }
                if (s4 < 3) {
                    #pragma unroll
                    for (int kk = 0; kk < 4; kk++) { c0v[kk] = n0[kk]; c1v[kk] = n1[kk]; }
                }
            }
            first = false;
            if (lane == 0)   // lane-0 only: counter==6 truly means all 6 waves
                __hip_atomic_fetch_add(&prod_done[k], 1, __ATOMIC_RELEASE, WG);
        }
        return;
    }

    // ======= CONSUMER (wave 0): 1-col-per-lane skew, COLPASS verbatim ========
    // Slot s: lane t processes D column (s - t), clamped to [0,387]. Lane t's
    // up/diag seeds = lane t-1's bottom of cols (s-t), (s-t-1), received via
    // one shfl per slot (rcv_up) with the previous value kept as rcv_diag.
    const int t = lane;
    {
        int g = 0;
        while (__hip_atomic_load(&prod_done[0], __ATOMIC_ACQUIRE, WG) < 6)
            if (++g > (1 << 22)) break;
    }
    __builtin_amdgcn_s_setprio(1);         // favor the DP wave on its SIMD
    const unsigned short* __restrict__ ringT = ring + 6 * t;

    float prev[6];                         // this lane's previous column values
    #pragma unroll
    for (int r = 0; r < 6; r++) prev[r] = KINF2;

    uint3 dslot[4];                        // FIFO: dslot[j] holds col (s - t + j)
    #pragma unroll
    for (int j = 0; j < 4; j++) {
        int c = j - t;
        int cc = c < 0 ? 0 : c;            // clamp low (< RING always here)
        dslot[j] = *(const uint3*)(ringT + (long)cc * RSTRIDE);
    }

    float rcv_up = KINF2, rcv_diag = KINF2;
    float lane0_diag = 0.0f;               // R[0][0]; KINF2 afterwards
    const bool isl0 = (t == 0);
    int kdone = 0;

#define UNPACK(d, w)                                                        \
    d[0] = __uint_as_float(w.x << 16);                                      \
    d[1] = __uint_as_float(w.x & 0xFFFF0000u);                              \
    d[2] = __uint_as_float(w.y << 16);                                      \
    d[3] = __uint_as_float(w.y & 0xFFFF0000u);                              \
    d[4] = __uint_as_float(w.z << 16);                                      \
    d[5] = __uint_as_float(w.z & 0xFFFF0000u);

#define COLPASS(dX, diag0, upseed, LEFTV, NEWV)                             \
    {                                                                       \
        float Bp = (upseed), Fp = 1.0f;                                     \
        float Bv[6], Fv[6];                                                 \
        _Pragma("unroll")                                                   \
        for (int r = 0; r < 6; r++) {                                       \
            float vd = (r == 0) ? (diag0) : LEFTV[r - 1];                   \
            float vl = LEFTV[r];                                            \
            float m3 = fminf(fminf(vd, vl), Bp);     /* v_min3_f32 */       \
            float al = EXP2F(m3 - Bp);                                      \
            float be = EXP2F(m3 - vd) + EXP2F(m3 - vl);                     \
            float Fr = __builtin_fmaf(al, Fp, be);                          \
            float Br = dX[r] + m3;                                          \
            Bv[r] = Br; Fv[r] = Fr;                                         \
            Bp = Br; Fp = Fr;                                               \
        }                                                                   \
        _Pragma("unroll")                                                   \
        for (int r = 0; r < 6; r++)                                         \
            NEWV[r] = Bv[r] - LOG2F(Fv[r]);                                 \
    }

    // One column-slot: consume dslot[J], refill it with col (S+4-t), COLPASS
    // in place (prev -> prev), rotate boundary registers, one shfl.
#define SLOT(J, S)                                                          \
    {                                                                       \
        uint3 w = dslot[J];                                                 \
        {   int cn = (S) + 4 - t;                                           \
            int cc = cn < 0 ? 0 : (cn > 387 ? 387 : cn);                    \
            int sl = cc >= RING ? cc - RING : cc;                           \
            dslot[J] = *(const uint3*)(ringT + (long)sl * RSTRIDE);         \
        }                                                                   \
        float d6[6];                                                        \
        UNPACK(d6, w)                                                       \
        float dg = isl0 ? lane0_diag : rcv_diag;                            \
        float up = isl0 ? KINF2 : rcv_up;                                   \
        COLPASS(d6, dg, up, prev, prev)                                     \
        rcv_diag = rcv_up;                                                  \
        rcv_up = __shfl_up(prev[5], 1, 64);                                 \
        lane0_diag = KINF2;                                                 \
    }

    for (int i = 0; i < 111; i++) {        // slots 0..443
        int kr = (4 * i + 7) >> 5;         // chunk needed by this group's refills
        if (kr > 12) kr = 12;
        if (kr > kdone) {
            int g = 0;
            while (__hip_atomic_load(&prod_done[kr], __ATOMIC_ACQUIRE, WG) < 6)
                if (++g > (1 << 22)) break;
            kdone = kr;
        }
        SLOT(0, 4 * i)
        SLOT(1, 4 * i + 1)
        SLOT(2, 4 * i + 2)
        SLOT(3, 4 * i + 3)
        if ((i & 1) && t == 0)             // publish every 8 slots (release =>
            __hip_atomic_store(&cons_sl, 4 * i + 3,  // lgkm drain: reads durable)
                               __ATOMIC_RELEASE, WG);
    }
    SLOT(0, 444)                           // epilogue slots 444..446
    SLOT(1, 445)
    SLOT(2, 446)
#undef SLOT
#undef COLPASS
#undef UNPACK

    // lane 63, slot 446 = D col 383 (DP col 384): prev[5] = R[384][384]
    if (t == 63) out[bat] = prev[5] * LN2;
}

// ---------------------------------------------------------------------------
extern "C" void kernel_launch(void* const* d_in, const int* in_sizes, int n_in,
                              void* d_out, int out_size, void* d_ws, size_t ws_size,
                              hipStream_t stream) {
    (void)in_sizes; (void)n_in; (void)out_size; (void)d_ws; (void)ws_size;
    const float* a = (const float*)d_in[0];
    const float* b = (const float*)d_in[1];
    float* out = (float*)d_out;

    fused_dtw<<<dim3(BATCH), dim3(512), 0, stream>>>(a, b, out);
}

// Round 10
// 183.953 us; speedup vs baseline: 1.8324x; 1.0163x over previous
//
#include <hip/hip_runtime.h>
#include <stdint.h>

// Problem constants (fixed by the reference setup_inputs)
#define BATCH 128
#define SEQN  384
#define SEQM  384
#define DIM   128
#define KINF   1000000.0f                 // reference pseudo-infinity (nat units)
#define LOG2E  1.4426950408889634f
#define LN2    0.6931471805599453f
#define KINF2  (KINF * LOG2E)             // pseudo-infinity in base-2-scaled units

// Fused producer/consumer geometry
#define RING    204                       // LDS ring capacity in D-columns
#define RSTRIDE 392                       // ushorts per ring column (conflict-free banks)

// hardware base-2 transcendentals (v_exp_f32 / v_log_f32)
#define EXP2F(x) __builtin_amdgcn_exp2f(x)
#define LOG2F(x) __builtin_amdgcn_logf(x)

#define WG __HIP_MEMORY_SCOPE_WORKGROUP

typedef __attribute__((ext_vector_type(8))) short bf16x8;   // 8 bf16 = 4 VGPRs (MFMA A/B frag)
typedef __attribute__((ext_vector_type(4))) float f32x4;    // MFMA C/D frag

__device__ __forceinline__ unsigned short bf16_rne(float x) {
    uint32_t u = __float_as_uint(x);
    u += 0x7FFFu + ((u >> 16) & 1u);
    return (unsigned short)(u >> 16);
}
__device__ __forceinline__ uint32_t bf16_pair(float x, float y) {
    uint32_t ux = __float_as_uint(x); ux += 0x7FFFu + ((ux >> 16) & 1u);
    uint32_t uy = __float_as_uint(y); uy += 0x7FFFu + ((uy >> 16) & 1u);
    return (ux >> 16) | (uy & 0xFFFF0000u);
}

// DPP wavefront-shift-right-by-1: lane n <- lane n-1 (== __shfl_up(x,1,64))
// as a pure 2-cyc VALU op — no ds_bpermute, no lgkmcnt coupling with the
// refill ds_read FIFO. Lane 0 gets `old`(=0); lane 0 never consumes it.
__device__ __forceinline__ float dpp_shfl_up1(float x) {
    return __int_as_float(__builtin_amdgcn_update_dpp(
        0, (int)__float_as_uint(x), 0x138 /*WAVE_SHR1*/, 0xF, 0xF, false));
}

union frag_u { bf16x8 v; uint32_t u[4]; };

// ---------------------------------------------------------------------------
// Fused kernel: one block per batch, 8 waves (512 thr), 1 block/CU.
//   wave 0        : soft-DTW DP consumer, 1-column-per-lane skew (447 slots).
//                   NEW vs r9: boundary pass lane->lane+1 via DPP wave_shr:1
//                   instead of ds_bpermute — removes ~50cyc LDS latency from
//                   the serial cross-slot chain AND decouples the refill
//                   ds_read FIFO from lgkmcnt(0) drains (counted waits now).
//   wave 4        : pad-column writer (cols 384..387 -> ring slots 180..183),
//                   sleeps until cons_sl >= 248, writes, exits.
//   waves 1-3,5-7 : 6 producers (pidx 0..5), r8-verbatim chunk pipeline.
//                   Ring-wrap gate: cons_sl >= 32k-110 (slot units).
// ---------------------------------------------------------------------------
__global__ __launch_bounds__(512) void fused_dtw(
        const float* __restrict__ A, const float* __restrict__ B,
        float* __restrict__ out) {
    __shared__ __align__(16) unsigned short ring[RING * RSTRIDE]; // 159,936 B
    __shared__ __align__(16) float normA[SEQN];                   //   1,536 B
    __shared__ int prod_done[16];
    __shared__ int cons_sl;

    const int bat  = blockIdx.x;
    const int tid  = threadIdx.x;
    const int wv   = tid >> 6;
    const int lane = tid & 63;

    if (tid < 16) prod_done[tid] = 0;
    if (tid == 16) cons_sl = -1;
    __syncthreads();                       // only block-wide sync in the kernel

    if (wv == 4) {
        // ================= PAD WRITER (wave 4, shares SIMD0) =================
        // slots 180..183 hold cols 180..183 until consumer slot 242; gate 248.
        int g = 0;
        while (__hip_atomic_load(&cons_sl, __ATOMIC_ACQUIRE, WG) < 248) {
            __builtin_amdgcn_s_sleep(8);   // ~512 cyc naps: no issue pressure
            if (++g > (1 << 20)) break;
        }
        uint32_t pv = bf16_pair(KINF2, KINF2);
        #pragma unroll
        for (int c = 0; c < 4; c++) {
            uint32_t* p = (uint32_t*)&ring[(384 - RING + c) * RSTRIDE + 6 * lane];
            p[0] = pv; p[1] = pv; p[2] = pv;
        }
        if (lane == 0)
            __hip_atomic_fetch_add(&prod_done[12], 6, __ATOMIC_RELEASE, WG);
        return;
    }

    if (wv != 0) {
        // ============== PRODUCERS (waves 1,2,3,5,6,7 -> pidx 0..5) ===========
        const int pidx  = (wv < 4) ? (wv - 1) : (wv - 2);
        const int sbase = pidx * 4;        // this wave's 4 si-groups (of 24)
        const int l16 = lane & 15, q = lane >> 4;
        const float* __restrict__ Ab = A + (long)bat * SEQN * DIM;
        const float* __restrict__ Bb = B + (long)bat * SEQM * DIM;
        bool first = true;
        for (int k = 0; k < 12; k++) {
            if (k >= 6) {
                // ring-wrap safety, slot units: thr = 32k-110.
                int thr = 32 * k - 110, g = 0;
                while (__hip_atomic_load(&cons_sl, __ATOMIC_ACQUIRE, WG) < thr) {
                    __builtin_amdgcn_s_sleep(2);
                    if (++g > (1 << 21)) break;
                }
            }
            // ---- B fragments for 32 cols (2 j-groups of 16) + b-norms ----
            frag_u bfrag[2][4];
            float bn[2];
            #pragma unroll
            for (int jg = 0; jg < 2; jg++) {
                const float* bp = Bb + (long)(32 * k + jg * 16 + l16) * DIM + q * 8;
                float s = 0.0f;
                #pragma unroll
                for (int kk = 0; kk < 4; kk++) {
                    float4 v0 = *(const float4*)(bp + kk * 32);
                    float4 v1 = *(const float4*)(bp + kk * 32 + 4);
                    bfrag[jg][kk].u[0] = bf16_pair(v0.x, v0.y);
                    bfrag[jg][kk].u[1] = bf16_pair(v0.z, v0.w);
                    bfrag[jg][kk].u[2] = bf16_pair(v1.x, v1.y);
                    bfrag[jg][kk].u[3] = bf16_pair(v1.z, v1.w);
                    s += v0.x*v0.x + v0.y*v0.y + v0.z*v0.z + v0.w*v0.w
                       + v1.x*v1.x + v1.y*v1.y + v1.z*v1.z + v1.w*v1.w;
                }
                s += __shfl_xor(s, 16, 64);
                s += __shfl_xor(s, 32, 64);
                bn[jg] = s;                // norm of this lane's j row
            }
            // ---- this wave's 4 si-groups, 1-deep A prefetch ----
            float4 c0v[4], c1v[4];
            {
                const float* ap = Ab + (long)(sbase * 16 + l16) * DIM + q * 8;
                #pragma unroll
                for (int kk = 0; kk < 4; kk++) {
                    c0v[kk] = *(const float4*)(ap + kk * 32);
                    c1v[kk] = *(const float4*)(ap + kk * 32 + 4);
                }
            }
            #pragma unroll
            for (int s4 = 0; s4 < 4; s4++) {
                const int si = sbase + s4;
                float4 n0[4], n1[4];
                if (s4 < 3) {              // prefetch next si-group
                    const float* ap = Ab + (long)((si + 1) * 16 + l16) * DIM + q * 8;
                    #pragma unroll
                    for (int kk = 0; kk < 4; kk++) {
                        n0[kk] = *(const float4*)(ap + kk * 32);
                        n1[kk] = *(const float4*)(ap + kk * 32 + 4);
                    }
                }
                frag_u afr[4];
                #pragma unroll
                for (int kk = 0; kk < 4; kk++) {
                    afr[kk].u[0] = bf16_pair(c0v[kk].x, c0v[kk].y);
                    afr[kk].u[1] = bf16_pair(c0v[kk].z, c0v[kk].w);
                    afr[kk].u[2] = bf16_pair(c1v[kk].x, c1v[kk].y);
                    afr[kk].u[3] = bf16_pair(c1v[kk].z, c1v[kk].w);
                }
                if (first) {               // this wave's normA slice (own rows)
                    float sa = 0.0f;
                    #pragma unroll
                    for (int kk = 0; kk < 4; kk++)
                        sa += c0v[kk].x*c0v[kk].x + c0v[kk].y*c0v[kk].y
                            + c0v[kk].z*c0v[kk].z + c0v[kk].w*c0v[kk].w
                            + c1v[kk].x*c1v[kk].x + c1v[kk].y*c1v[kk].y
                            + c1v[kk].z*c1v[kk].z + c1v[kk].w*c1v[kk].w;
                    sa += __shfl_xor(sa, 16, 64);
                    sa += __shfl_xor(sa, 32, 64);
                    if (q == 0) normA[si * 16 + l16] = sa;
                }
                f32x4 acc0 = {0.0f, 0.0f, 0.0f, 0.0f};
                f32x4 acc1 = {0.0f, 0.0f, 0.0f, 0.0f};
                #pragma unroll
                for (int kk = 0; kk < 4; kk++) {
                    acc0 = __builtin_amdgcn_mfma_f32_16x16x32_bf16(
                               afr[kk].v, bfrag[0][kk].v, acc0, 0, 0, 0);
                    acc1 = __builtin_amdgcn_mfma_f32_16x16x32_bf16(
                               afr[kk].v, bfrag[1][kk].v, acc1, 0, 0, 0);
                }
                if (first) asm volatile("s_waitcnt lgkmcnt(0)" ::: "memory");
                float4 an = *(const float4*)&normA[si * 16 + q * 4];
                #pragma unroll
                for (int jg = 0; jg < 2; jg++) {
                    int col  = 32 * k + jg * 16 + l16;
                    int slot = col >= RING ? col - RING : col;
                    f32x4 ac = jg ? acc1 : acc0;
                    ushort4 pk;
                    pk.x = bf16_rne((an.x + bn[jg] - 2.0f * ac[0]) * LOG2E);
                    pk.y = bf16_rne((an.y + bn[jg] - 2.0f * ac[1]) * LOG2E);
                    pk.z = bf16_rne((an.z + bn[jg] - 2.0f * ac[2]) * LOG2E);
                    pk.w = bf16_rne((an.w + bn[jg] - 2.0f * ac[3]) * LOG2E);
                    *(ushort4*)&ring[slot * RSTRIDE + si * 16 + q * 4] = pk;
                }
                if (s4 < 3) {
                    #pragma unroll
                    for (int kk = 0; kk < 4; kk++) { c0v[kk] = n0[kk]; c1v[kk] = n1[kk]; }
                }
            }
            first = false;
            if (lane == 0)   // lane-0 only: counter==6 truly means all 6 waves
                __hip_atomic_fetch_add(&prod_done[k], 1, __ATOMIC_RELEASE, WG);
        }
        return;
    }

    // ======= CONSUMER (wave 0): 1-col-per-lane skew, DPP boundary pass =======
    // Slot s: lane t processes D column (s - t), clamped to [0,387]. Lane t's
    // up/diag seeds = lane t-1's bottom of cols (s-t), (s-t-1), via DPP.
    const int t = lane;
    {
        int g = 0;
        while (__hip_atomic_load(&prod_done[0], __ATOMIC_ACQUIRE, WG) < 6)
            if (++g > (1 << 22)) break;
    }
    __builtin_amdgcn_s_setprio(1);         // favor the DP wave on its SIMD
    const unsigned short* __restrict__ ringT = ring + 6 * t;

    float prev[6];                         // this lane's previous column values
    #pragma unroll
    for (int r = 0; r < 6; r++) prev[r] = KINF2;

    uint3 dslot[4];                        // FIFO: dslot[j] holds col (s - t + j)
    #pragma unroll
    for (int j = 0; j < 4; j++) {
        int c = j - t;
        int cc = c < 0 ? 0 : c;            // clamp low (< RING always here)
        dslot[j] = *(const uint3*)(ringT + (long)cc * RSTRIDE);
    }

    float rcv_up = KINF2, rcv_diag = KINF2;
    float lane0_diag = 0.0f;               // R[0][0]; KINF2 afterwards
    const bool isl0 = (t == 0);
    int kdone = 0;

#define UNPACK(d, w)                                                        \
    d[0] = __uint_as_float(w.x << 16);                                      \
    d[1] = __uint_as_float(w.x & 0xFFFF0000u);                              \
    d[2] = __uint_as_float(w.y << 16);                                      \
    d[3] = __uint_as_float(w.y & 0xFFFF0000u);                              \
    d[4] = __uint_as_float(w.z << 16);                                      \
    d[5] = __uint_as_float(w.z & 0xFFFF0000u);

#define COLPASS(dX, diag0, upseed, LEFTV, NEWV)                             \
    {                                                                       \
        float Bp = (upseed), Fp = 1.0f;                                     \
        float Bv[6], Fv[6];                                                 \
        _Pragma("unroll")                                                   \
        for (int r = 0; r < 6; r++) {                                       \
            float vd = (r == 0) ? (diag0) : LEFTV[r - 1];                   \
            float vl = LEFTV[r];                                            \
            float m3 = fminf(fminf(vd, vl), Bp);     /* v_min3_f32 */       \
            float al = EXP2F(m3 - Bp);                                      \
            float be = EXP2F(m3 - vd) + EXP2F(m3 - vl);                     \
            float Fr = __builtin_fmaf(al, Fp, be);                          \
            float Br = dX[r] + m3;                                          \
            Bv[r] = Br; Fv[r] = Fr;                                         \
            Bp = Br; Fp = Fr;                                               \
        }                                                                   \
        _Pragma("unroll")                                                   \
        for (int r = 0; r < 6; r++)                                         \
            NEWV[r] = Bv[r] - LOG2F(Fv[r]);                                 \
    }

    // One column-slot: consume dslot[J], refill it with col (S+4-t), COLPASS
    // in place (prev -> prev), rotate boundary registers, one DPP shift.
#define SLOT(J, S)                                                          \
    {                                                                       \
        uint3 w = dslot[J];                                                 \
        {   int cn = (S) + 4 - t;                                           \
            int cc = cn < 0 ? 0 : (cn > 387 ? 387 : cn);                    \
            int sl = cc >= RING ? cc - RING : cc;                           \
            dslot[J] = *(const uint3*)(ringT + (long)sl * RSTRIDE);         \
        }                                                                   \
        float d6[6];                                                        \
        UNPACK(d6, w)                                                       \
        float dg = isl0 ? lane0_diag : rcv_diag;                            \
        float up = isl0 ? KINF2 : rcv_up;                                   \
        COLPASS(d6, dg, up, prev, prev)                                     \
        rcv_diag = rcv_up;                                                  \
        rcv_up = dpp_shfl_up1(prev[5]);                                     \
        lane0_diag = KINF2;                                                 \
    }

    for (int i = 0; i < 111; i++) {        // slots 0..443
        int kr = (4 * i + 7) >> 5;         // chunk needed by this group's refills
        if (kr > 12) kr = 12;
        if (kr > kdone) {
            int g = 0;
            while (__hip_atomic_load(&prod_done[kr], __ATOMIC_ACQUIRE, WG) < 6)
                if (++g > (1 << 22)) break;
            kdone = kr;
        }
        SLOT(0, 4 * i)
        SLOT(1, 4 * i + 1)
        SLOT(2, 4 * i + 2)
        SLOT(3, 4 * i + 3)
        if ((i & 1) && t == 0)             // publish every 8 slots (release =>
            __hip_atomic_store(&cons_sl, 4 * i + 3,  // lgkm drain: reads durable)
                               __ATOMIC_RELEASE, WG);
    }
    SLOT(0, 444)                           // epilogue slots 444..446
    SLOT(1, 445)
    SLOT(2, 446)
#undef SLOT
#undef COLPASS
#undef UNPACK

    // lane 63, slot 446 = D col 383 (DP col 384): prev[5] = R[384][384]
    if (t == 63) out[bat] = prev[5] * LN2;
}

// ---------------------------------------------------------------------------
extern "C" void kernel_launch(void* const* d_in, const int* in_sizes, int n_in,
                              void* d_out, int out_size, void* d_ws, size_t ws_size,
                              hipStream_t stream) {
    (void)in_sizes; (void)n_in; (void)out_size; (void)d_ws; (void)ws_size;
    const float* a = (const float*)d_in[0];
    const float* b = (const float*)d_in[1];
    float* out = (float*)d_out;

    fused_dtw<<<dim3(BATCH), dim3(512), 0, stream>>>(a, b, out);
}